// Round 7
// baseline (620.422 us; speedup 1.0000x reference)
//
#include <hip/hip_runtime.h>
#include <cstdint>
#include <cstddef>

#define DIM 2048
#define NROWS 8192
#define NL 3
#define DEPTH 5
#define NLK 18            // NL*(DEPTH+1)
#define NCB 16            // col-blocks (DIM/128) contributing partials per row
#define CF_EPS 0.01f

// ---------------------------------------------------------------- MFMA GEMM
typedef __attribute__((ext_vector_type(8))) __bf16 bfrag;   // 8 bf16 = 4 VGPRs
typedef __attribute__((ext_vector_type(4))) float f32x4;

typedef __attribute__((address_space(1))) void gvoid;
typedef __attribute__((address_space(3))) void lvoid;

__device__ __forceinline__ void gld_lds16(const void* g, void* l) {
    // async global->LDS, 16B per lane, dest = wave-uniform base + lane*16
    __builtin_amdgcn_global_load_lds((gvoid*)g, (lvoid*)l, 16, 0, 0);
}

// ================================================================
// MIXED GEMM (block specialization for CU co-scheduling, m114):
//   grid (32, 64); even blockIdx.x -> GATE block, odd -> U block.
//   Gate blocks: split-bf16 3-chain 128x128 tile + in-block gated-
//     ladder reduction -> a_part    (proven round-2/5 code, 252us solo)
//   U blocks: Xh x Uwh 128x128 tile, 2 sub-tiles per barrier pair,
//     raw C-write to out            (proven round-5 code)
// Rationale: gate solo = 36% Mfma + 37% VALU + ~25% barrier drain;
// U solo = mostly stall (same loop, 1/3 the MFMA). Serial execution
// alternates saturated/starved; interleaved heterogeneous blocks on
// one CU co-schedule at ~max not sum (m114). Parity on fastest
// dispatch dim interleaves types across CUs.
// Both paths keep their proven internals: 32KB LDS, static epilogue
// (rule #20), no swizzle changes (rule #21).
// ================================================================
__global__ __launch_bounds__(256) void gemm_mixed(
    const ushort* __restrict__ Xh, const ushort* __restrict__ Xl,
    const ushort* __restrict__ Gwh, const ushort* __restrict__ Gwl,
    const ushort* __restrict__ Uwh,
    const float* __restrict__ X,  const float* __restrict__ Lw,
    float* __restrict__ outU, float* __restrict__ a_part)
{
    constexpr int BK = 32;
    __shared__ __align__(16) char smem[32768];

    const int tid  = threadIdx.x;
    const int wave = tid >> 6;
    const int lane = tid & 63;
    const int wm   = wave & 1;
    const int wn   = wave >> 1;
    const int bx   = blockIdx.x;           // 0..31
    const int cb   = bx >> 1;              // col block 0..15
    const int m0   = blockIdx.y * 128;
    const int n0   = cb * 128;

    const int fm = lane & 15;
    const int fq = lane >> 4;

    const size_t soff = (size_t)(wave * 32 + (lane >> 2)) * DIM + (lane & 3) * 8;

    if (bx & 1) {
        // ===================== U path (2 sub-tiles / barrier pair) =====================
        constexpr int SUB = 128 * BK;                // ushorts per sub-tile
        ushort* sA = (ushort*)smem;                  // [2*SUB] = 16KB
        ushort* sB = (ushort*)(smem + 16384);        // [2*SUB] = 16KB

        const ushort* gA = Xh  + (size_t)m0 * DIM + soff;
        const ushort* gB = Uwh + (size_t)n0 * DIM + soff;

        ushort* lA0 = &sA[(wave * 32) * BK];
        ushort* lA1 = &sA[(wave * 32 + 16) * BK];
        ushort* lB0 = &sB[(wave * 32) * BK];
        ushort* lB1 = &sB[(wave * 32 + 16) * BK];

        f32x4 acc[4][4];
        #pragma unroll
        for (int i = 0; i < 4; ++i)
            #pragma unroll
            for (int j = 0; j < 4; ++j)
                acc[i][j] = (f32x4){0.f, 0.f, 0.f, 0.f};

        for (int k0 = 0; k0 < DIM; k0 += 2 * BK) {
            __syncthreads();                          // previous step consumed
            gld_lds16(gA + k0, lA0);
            gld_lds16(gA + (size_t)16 * DIM + k0, lA1);
            gld_lds16(gB + k0, lB0);
            gld_lds16(gB + (size_t)16 * DIM + k0, lB1);
            gld_lds16(gA + k0 + BK, lA0 + SUB);
            gld_lds16(gA + (size_t)16 * DIM + k0 + BK, lA1 + SUB);
            gld_lds16(gB + k0 + BK, lB0 + SUB);
            gld_lds16(gB + (size_t)16 * DIM + k0 + BK, lB1 + SUB);
            __syncthreads();                          // vmcnt(0) drained by barrier

            #pragma unroll
            for (int ks = 0; ks < 2; ++ks) {
                const ushort* pA = &sA[ks * SUB];
                const ushort* pB = &sB[ks * SUB];
                bfrag ah[4], bh[4];
                #pragma unroll
                for (int i = 0; i < 4; ++i) {
                    ah[i] = *(const bfrag*)&pA[(wm * 64 + i * 16 + fm) * BK + fq * 8];
                    bh[i] = *(const bfrag*)&pB[(wn * 64 + i * 16 + fm) * BK + fq * 8];
                }
                #pragma unroll
                for (int i = 0; i < 4; ++i)
                    #pragma unroll
                    for (int j = 0; j < 4; ++j)
                        acc[i][j] = __builtin_amdgcn_mfma_f32_16x16x32_bf16(ah[i], bh[j], acc[i][j], 0, 0, 0);
            }
        }

        // raw C-write; z*V^T added later by zv_cf_add
        // C/D layout: col = lane&15, row = (lane>>4)*4 + reg
        #pragma unroll
        for (int i = 0; i < 4; ++i) {
            const int rowb = m0 + wm * 64 + i * 16 + fq * 4;
            #pragma unroll
            for (int j = 0; j < 4; ++j) {
                const int col = n0 + wn * 64 + j * 16 + fm;
                #pragma unroll
                for (int r = 0; r < 4; ++r)
                    outU[(size_t)(rowb + r) * DIM + col] = acc[i][j][r];
            }
        }
        return;
    }

    // ===================== gate path (split-bf16 3-chain + ladder) =====================
    // [0,32768): staging 4 x 128x32 bf16 tiles (8KB each)
    // epilogue aliases: sG [0,16896) = 32x132 fp32 ; sLw [16896,28128) = 18x156 fp32
    ushort* sAh = (ushort*)(smem);
    ushort* sBh = (ushort*)(smem + 8192);
    ushort* sAl = (ushort*)(smem + 16384);
    ushort* sBl = (ushort*)(smem + 24576);
    float*  sG  = (float*)(smem);            // quarter-tile of gated values
    float*  sLw = (float*)(smem + 16896);    // ladder weights, strip-swizzled

    const ushort* gA  = Xh  + (size_t)m0 * DIM + soff;
    const ushort* gAl = Xl  + (size_t)m0 * DIM + soff;
    const ushort* gB  = Gwh + (size_t)n0 * DIM + soff;
    const ushort* gBl = Gwl + (size_t)n0 * DIM + soff;

    ushort* lA0  = &sAh[(wave * 32) * BK];
    ushort* lA1  = &sAh[(wave * 32 + 16) * BK];
    ushort* lB0  = &sBh[(wave * 32) * BK];
    ushort* lB1  = &sBh[(wave * 32 + 16) * BK];
    ushort* lAl0 = &sAl[(wave * 32) * BK];
    ushort* lAl1 = &sAl[(wave * 32 + 16) * BK];
    ushort* lBl0 = &sBl[(wave * 32) * BK];
    ushort* lBl1 = &sBl[(wave * 32 + 16) * BK];

    f32x4 acc[4][4];
    #pragma unroll
    for (int i = 0; i < 4; ++i)
        #pragma unroll
        for (int j = 0; j < 4; ++j)
            acc[i][j] = (f32x4){0.f, 0.f, 0.f, 0.f};

    for (int k0 = 0; k0 < DIM; k0 += BK) {
        __syncthreads();
        gld_lds16(gA + k0, lA0);
        gld_lds16(gA + (size_t)16 * DIM + k0, lA1);
        gld_lds16(gB + k0, lB0);
        gld_lds16(gB + (size_t)16 * DIM + k0, lB1);
        gld_lds16(gAl + k0, lAl0);
        gld_lds16(gAl + (size_t)16 * DIM + k0, lAl1);
        gld_lds16(gBl + k0, lBl0);
        gld_lds16(gBl + (size_t)16 * DIM + k0, lBl1);
        __syncthreads();

        bfrag ah[4], bh[4], al[4], bl[4];
        #pragma unroll
        for (int i = 0; i < 4; ++i) {
            ah[i] = *(const bfrag*)&sAh[(wm * 64 + i * 16 + fm) * BK + fq * 8];
            bh[i] = *(const bfrag*)&sBh[(wn * 64 + i * 16 + fm) * BK + fq * 8];
            al[i] = *(const bfrag*)&sAl[(wm * 64 + i * 16 + fm) * BK + fq * 8];
            bl[i] = *(const bfrag*)&sBl[(wn * 64 + i * 16 + fm) * BK + fq * 8];
        }
        #pragma unroll
        for (int i = 0; i < 4; ++i)
            #pragma unroll
            for (int j = 0; j < 4; ++j) {
                acc[i][j] = __builtin_amdgcn_mfma_f32_16x16x32_bf16(ah[i], bh[j], acc[i][j], 0, 0, 0);
                acc[i][j] = __builtin_amdgcn_mfma_f32_16x16x32_bf16(ah[i], bl[j], acc[i][j], 0, 0, 0);
                acc[i][j] = __builtin_amdgcn_mfma_f32_16x16x32_bf16(al[i], bh[j], acc[i][j], 0, 0, 0);
            }
    }

    // ---- fused gated-ladder reduction, four 32-row quarters (STATIC) ----
    const float* xblk = X + (size_t)m0 * DIM + n0;
    const int rred  = ((tid >> 6) << 3) | (tid & 7);   // reduce row 0..31
    const int strip = (lane >> 3) & 7;                 // 8 strips x 16 cols
    const int qc    = strip * 16;

#define DO_QUARTER(Q)                                                          \
    {                                                                          \
        __syncthreads();  /* staging (Q==0) / previous-quarter reads done */   \
        if (Q == 0) {                                                          \
            /* ladder weights, strip-swizzled (+4 dwords per 16-col strip) */  \
            for (int idx = tid; idx < NLK * 128; idx += 256) {                 \
                const int lk = idx >> 7, c = idx & 127;                        \
                sLw[lk * 156 + c + ((c >> 4) << 2)] = Lw[(size_t)lk * DIM + n0 + c]; \
            }                                                                  \
        }                                                                      \
        if (wm == (Q >> 1)) {                                                  \
            constexpr int ib = (Q & 1) * 2;  /* compile-time: keeps acc in VGPRs */ \
            _Pragma("unroll")                                                  \
            for (int ii = 0; ii < 2; ++ii) {                                   \
                _Pragma("unroll")                                              \
                for (int r = 0; r < 4; ++r) {                                  \
                    const int rloc = ii * 16 + fq * 4 + r;      /* 0..31 */    \
                    const float* xr = xblk + (size_t)(Q * 32 + rloc) * DIM;    \
                    _Pragma("unroll")                                          \
                    for (int j = 0; j < 4; ++j) {                              \
                        const int cc = wn * 64 + j * 16 + fm;                  \
                        const float g = acc[ib + ii][j][r];                    \
                        const float s = 1.0f / (1.0f + __expf(-g));            \
                        sG[rloc * 132 + cc] = s * xr[cc];                      \
                    }                                                          \
                }                                                              \
            }                                                                  \
        }                                                                      \
        __syncthreads();   /* sG (+ sLw at Q==0) ready */                      \
        float p[NLK];                                                          \
        _Pragma("unroll")                                                      \
        for (int lk = 0; lk < NLK; ++lk) p[lk] = 0.f;                          \
        _Pragma("unroll")                                                      \
        for (int c4 = 0; c4 < 16; c4 += 4) {                                   \
            const float4 g4 = *(const float4*)&sG[rred * 132 + qc + c4];       \
            _Pragma("unroll")                                                  \
            for (int lk = 0; lk < NLK; ++lk) {                                 \
                const float4 w4 = *(const float4*)&sLw[lk * 156 + qc + c4 + (strip << 2)]; \
                p[lk] = fmaf(g4.x, w4.x, fmaf(g4.y, w4.y,                      \
                        fmaf(g4.z, w4.z, fmaf(g4.w, w4.w, p[lk]))));           \
            }                                                                  \
        }                                                                      \
        _Pragma("unroll")                                                      \
        for (int lk = 0; lk < NLK; ++lk) {                                     \
            p[lk] += __shfl_xor(p[lk], 8, 64);                                 \
            p[lk] += __shfl_xor(p[lk], 16, 64);                                \
            p[lk] += __shfl_xor(p[lk], 32, 64);                                \
        }                                                                      \
        if ((lane >> 3) == 0) {                                                \
            float* dst = a_part +                                              \
                ((size_t)(m0 + Q * 32 + rred) * NCB + cb) * NLK;               \
            _Pragma("unroll")                                                  \
            for (int lk = 0; lk < NLK; ++lk) dst[lk] = p[lk];                  \
        }                                                                      \
    }

    DO_QUARTER(0)
    DO_QUARTER(1)
    DO_QUARTER(2)
    DO_QUARTER(3)
#undef DO_QUARTER
}

// ================================================================
// Per-row: reduce ladder partials -> continued fraction -> z, then
//   out[r, :] += z[r] . Vp[:, 0..2]      (round-4-proven RMW pass)
// ================================================================
__global__ __launch_bounds__(256) void zv_cf_add(
    float* __restrict__ out, const float* __restrict__ a_part,
    const float* __restrict__ Vp)
{
    __shared__ float red[NLK];
    __shared__ float zsh[NL];
    const int r = blockIdx.x;
    const int tid = threadIdx.x;

    if (tid < NLK) {
        const float* ap = a_part + (size_t)r * NCB * NLK + tid;
        float s = 0.f;
        #pragma unroll
        for (int cb = 0; cb < NCB; ++cb) s += ap[cb * NLK];
        red[tid] = s;
    }
    __syncthreads();
    if (tid < NL) {
        float f = 0.f;
        #pragma unroll
        for (int k = DEPTH - 1; k >= 0; --k) {
            float denom = 1.f + f;
            if (fabsf(denom) < CF_EPS) denom = (denom >= 0.f) ? CF_EPS : -CF_EPS;
            f = red[tid * 6 + k + 1] / denom;
        }
        zsh[tid] = red[tid * 6] + f;
    }
    __syncthreads();
    const float z0 = zsh[0], z1 = zsh[1], z2 = zsh[2];

    const int c0 = tid * 8;
    float* orow = out + (size_t)r * DIM + c0;
    const float4 o0 = *(const float4*)orow;
    const float4 o1 = *(const float4*)(orow + 4);
    float ov[8] = {o0.x, o0.y, o0.z, o0.w, o1.x, o1.y, o1.z, o1.w};
    #pragma unroll
    for (int j = 0; j < 8; ++j) {
        const float4 v = *(const float4*)&Vp[(size_t)(c0 + j) * 4];
        ov[j] += z0 * v.x + z1 * v.y + z2 * v.z;
    }
    *(float4*)orow       = make_float4(ov[0], ov[1], ov[2], ov[3]);
    *(float4*)(orow + 4) = make_float4(ov[4], ov[5], ov[6], ov[7]);
}

// V_w [2048][3] -> padded [2048][4] for aligned float4 loads
__global__ __launch_bounds__(256) void padV(const float* __restrict__ Vw,
                                            float* __restrict__ Vp)
{
    const int d = blockIdx.x * 256 + threadIdx.x;
    *(float4*)&Vp[(size_t)d * 4] =
        make_float4(Vw[(size_t)d * 3], Vw[(size_t)d * 3 + 1], Vw[(size_t)d * 3 + 2], 0.f);
}

// ---------------------------------------------------------------- prep
__device__ __forceinline__ ushort f2bf_bits(float f) {
    __bf16 h = (__bf16)f;                        // RNE
    return __builtin_bit_cast(unsigned short, h);
}
__device__ __forceinline__ float bfbits2f(ushort u) {
    __bf16 h = __builtin_bit_cast(__bf16, u);
    return (float)h;
}

union U16x8 { ushort u[8]; uint4 v; };

__global__ __launch_bounds__(256) void split2(const float* __restrict__ src,
                                              ushort* __restrict__ hi,
                                              ushort* __restrict__ lo)
{
    const size_t i0 = ((size_t)blockIdx.x * 256 + threadIdx.x) * 8;
    const float4 v0 = *(const float4*)(src + i0);
    const float4 v1 = *(const float4*)(src + i0 + 4);
    const float f[8] = {v0.x, v0.y, v0.z, v0.w, v1.x, v1.y, v1.z, v1.w};
    U16x8 h, l;
    #pragma unroll
    for (int j = 0; j < 8; ++j) {
        const ushort hb = f2bf_bits(f[j]);
        h.u[j] = hb;
        l.u[j] = f2bf_bits(f[j] - bfbits2f(hb));
    }
    *(uint4*)(hi + i0) = h.v;
    *(uint4*)(lo + i0) = l.v;
}

__global__ __launch_bounds__(256) void tobf16(const float* __restrict__ src,
                                              ushort* __restrict__ dst)
{
    const size_t i0 = ((size_t)blockIdx.x * 256 + threadIdx.x) * 8;
    const float4 v0 = *(const float4*)(src + i0);
    const float4 v1 = *(const float4*)(src + i0 + 4);
    const float f[8] = {v0.x, v0.y, v0.z, v0.w, v1.x, v1.y, v1.z, v1.w};
    U16x8 h;
    #pragma unroll
    for (int j = 0; j < 8; ++j) h.u[j] = f2bf_bits(f[j]);
    *(uint4*)(dst + i0) = h.v;
}

// ---------------------------------------------------------------- fp32 fallback GEMM (round-1, proven)
#define BMF 128
#define BNF 128
#define BKF 16
#define LDAF 132

__global__ __launch_bounds__(256) void sgemm_dual(
    const float* __restrict__ X,
    const float* __restrict__ Uw,
    const float* __restrict__ Gw,
    float* __restrict__ outLin,
    float* __restrict__ outGate)
{
    __shared__ float As[BKF][LDAF];
    __shared__ float Bs[BKF][LDAF];

    const int tid = threadIdx.x;
    const int n0 = blockIdx.x * BNF;
    const int m0 = blockIdx.y * BMF;
    const bool isGate = (n0 >= DIM);
    const float* W = isGate ? Gw : Uw;
    float* C = isGate ? outGate : outLin;
    const int nb = isGate ? (n0 - DIM) : n0;

    const int lr = tid >> 2;
    const int lc = (tid & 3) << 2;

    const float* pa0 = X + (size_t)(m0 + lr) * DIM + lc;
    const float* pa1 = X + (size_t)(m0 + lr + 64) * DIM + lc;
    const float* pb0 = W + (size_t)(nb + lr) * DIM + lc;
    const float* pb1 = W + (size_t)(nb + lr + 64) * DIM + lc;

    const int tx = tid & 15;
    const int ty = tid >> 4;

    float acc[8][8];
    #pragma unroll
    for (int i = 0; i < 8; ++i)
        #pragma unroll
        for (int j = 0; j < 8; ++j) acc[i][j] = 0.f;

    for (int k0 = 0; k0 < DIM; k0 += BKF) {
        const float4 a0 = *(const float4*)(pa0 + k0);
        const float4 a1 = *(const float4*)(pa1 + k0);
        const float4 b0 = *(const float4*)(pb0 + k0);
        const float4 b1 = *(const float4*)(pb1 + k0);
        __syncthreads();
        As[lc + 0][lr] = a0.x; As[lc + 1][lr] = a0.y; As[lc + 2][lr] = a0.z; As[lc + 3][lr] = a0.w;
        As[lc + 0][lr + 64] = a1.x; As[lc + 1][lr + 64] = a1.y; As[lc + 2][lr + 64] = a1.z; As[lc + 3][lr + 64] = a1.w;
        Bs[lc + 0][lr] = b0.x; Bs[lc + 1][lr] = b0.y; Bs[lc + 2][lr] = b0.z; Bs[lc + 3][lr] = b0.w;
        Bs[lc + 0][lr + 64] = b1.x; Bs[lc + 1][lr + 64] = b1.y; Bs[lc + 2][lr + 64] = b1.z; Bs[lc + 3][lr + 64] = b1.w;
        __syncthreads();
        #pragma unroll
        for (int kk = 0; kk < BKF; ++kk) {
            float av[8], bv[8];
            *(float4*)&av[0] = *(const float4*)&As[kk][ty * 8];
            *(float4*)&av[4] = *(const float4*)&As[kk][ty * 8 + 4];
            *(float4*)&bv[0] = *(const float4*)&Bs[kk][tx * 8];
            *(float4*)&bv[4] = *(const float4*)&Bs[kk][tx * 8 + 4];
            #pragma unroll
            for (int i = 0; i < 8; ++i)
                #pragma unroll
                for (int j = 0; j < 8; ++j)
                    acc[i][j] = fmaf(av[i], bv[j], acc[i][j]);
        }
    }

    #pragma unroll
    for (int i = 0; i < 8; ++i) {
        float* crow = C + (size_t)(m0 + ty * 8 + i) * DIM + nb + tx * 8;
        *(float4*)crow       = make_float4(acc[i][0], acc[i][1], acc[i][2], acc[i][3]);
        *(float4*)(crow + 4) = make_float4(acc[i][4], acc[i][5], acc[i][6], acc[i][7]);
    }
}

// ---------------------------------------------------------------- epilogue (fallback path only)
__global__ __launch_bounds__(256) void ladder_epilogue(
    const float* __restrict__ X,
    const float* __restrict__ G,
    const float* __restrict__ Lw,
    const float* __restrict__ Vw,
    float* __restrict__ Out)
{
    const int r = blockIdx.x;
    const int tid = threadIdx.x;
    const int d0 = tid * 8;
    const float* xrow = X + (size_t)r * DIM;
    const float* grow = G + (size_t)r * DIM;

    const float4 xv0 = *(const float4*)(xrow + d0);
    const float4 xv1 = *(const float4*)(xrow + d0 + 4);
    const float4 gv0 = *(const float4*)(grow + d0);
    const float4 gv1 = *(const float4*)(grow + d0 + 4);

    float gated[8];
    {
        const float gx[8] = {gv0.x, gv0.y, gv0.z, gv0.w, gv1.x, gv1.y, gv1.z, gv1.w};
        const float xx[8] = {xv0.x, xv0.y, xv0.z, xv0.w, xv1.x, xv1.y, xv1.z, xv1.w};
        #pragma unroll
        for (int j = 0; j < 8; ++j) {
            const float s = 1.0f / (1.0f + __expf(-gx[j]));
            gated[j] = s * xx[j];
        }
    }

    float part[NLK];
    #pragma unroll
    for (int lk = 0; lk < NLK; ++lk) {
        const float* lrow = Lw + (size_t)lk * DIM + d0;
        const float4 w0 = *(const float4*)lrow;
        const float4 w1 = *(const float4*)(lrow + 4);
        part[lk] = gated[0] * w0.x + gated[1] * w0.y + gated[2] * w0.z + gated[3] * w0.w
                 + gated[4] * w1.x + gated[5] * w1.y + gated[6] * w1.z + gated[7] * w1.w;
    }

    #pragma unroll
    for (int off = 32; off > 0; off >>= 1) {
        #pragma unroll
        for (int lk = 0; lk < NLK; ++lk)
            part[lk] += __shfl_down(part[lk], off, 64);
    }

    __shared__ float red[4][NLK];
    __shared__ float zsh[NL];
    const int wave = tid >> 6;
    const int lane = tid & 63;
    if (lane == 0) {
        #pragma unroll
        for (int lk = 0; lk < NLK; ++lk) red[wave][lk] = part[lk];
    }
    __syncthreads();
    if (tid < NL) {
        float a[DEPTH + 1];
        #pragma unroll
        for (int k = 0; k < DEPTH + 1; ++k)
            a[k] = red[0][tid * 6 + k] + red[1][tid * 6 + k]
                 + red[2][tid * 6 + k] + red[3][tid * 6 + k];
        float f = 0.f;
        #pragma unroll
        for (int k = DEPTH - 1; k >= 0; --k) {
            float denom = 1.f + f;
            if (fabsf(denom) < CF_EPS) denom = (denom >= 0.f) ? CF_EPS : -CF_EPS;
            f = a[k + 1] / denom;
        }
        zsh[tid] = a[0] + f;
    }
    __syncthreads();
    const float z0 = zsh[0], z1 = zsh[1], z2 = zsh[2];

    float* orow = Out + (size_t)r * DIM + d0;
    const float4 o0 = *(const float4*)orow;
    const float4 o1 = *(const float4*)(orow + 4);
    float ov[8] = {o0.x, o0.y, o0.z, o0.w, o1.x, o1.y, o1.z, o1.w};
    #pragma unroll
    for (int j = 0; j < 8; ++j) {
        const float* vp = Vw + (size_t)(d0 + j) * NL;
        ov[j] += z0 * vp[0] + z1 * vp[1] + z2 * vp[2];
    }
    *(float4*)orow       = make_float4(ov[0], ov[1], ov[2], ov[3]);
    *(float4*)(orow + 4) = make_float4(ov[4], ov[5], ov[6], ov[7]);
}

// ---------------------------------------------------------------- launch
extern "C" void kernel_launch(void* const* d_in, const int* in_sizes, int n_in,
                              void* d_out, int out_size, void* d_ws, size_t ws_size,
                              hipStream_t stream) {
    const float* X  = (const float*)d_in[0];
    const float* Uw = (const float*)d_in[1];
    const float* Gw = (const float*)d_in[2];
    const float* Lw = (const float*)d_in[3];
    const float* Vw = (const float*)d_in[4];
    float* out = (float*)d_out;

    // ws layout (bytes):
    //   Xh  bf16    @ 0           33554432
    //   Xl  bf16    @ 33554432    33554432
    //   Gwh bf16    @ 67108864     8388608
    //   Gwl bf16    @ 75497472     8388608
    //   Uwh bf16    @ 83886080     8388608
    //   a_part f32  @ 92274688     9437184   (8192 x 16 x 18)
    //   Vp  f32     @ 101711872      32768   (2048 x 4)
    const size_t WS_NEED = 101744640ull;
    char* ws = (char*)d_ws;

    if (ws_size >= WS_NEED) {
        ushort* Xh     = (ushort*)(ws);
        ushort* Xl     = (ushort*)(ws + 33554432);
        ushort* Gwh    = (ushort*)(ws + 67108864);
        ushort* Gwl    = (ushort*)(ws + 75497472);
        ushort* Uwh    = (ushort*)(ws + 83886080);
        float*  a_part = (float*)(ws + 92274688);
        float*  Vp     = (float*)(ws + 101711872);

        split2<<<dim3(8192), dim3(256), 0, stream>>>(X, Xh, Xl);       // 16.78M elems
        split2<<<dim3(2048), dim3(256), 0, stream>>>(Gw, Gwh, Gwl);    // 4.19M elems
        tobf16<<<dim3(2048), dim3(256), 0, stream>>>(Uw, Uwh);
        padV  <<<dim3(8),    dim3(256), 0, stream>>>(Vw, Vp);

        // grid (32, 64): even bx = gate block, odd bx = U block (interleaved
        // in dispatch order -> heterogeneous blocks co-resident per CU)
        gemm_mixed<<<dim3(32, 64), dim3(256), 0, stream>>>(Xh, Xl, Gwh, Gwl, Uwh,
                                                           X, Lw, out, a_part);
        zv_cf_add<<<dim3(NROWS), dim3(256), 0, stream>>>(out, a_part, Vp);
    } else {
        // fallback: round-1 fp32 path (needs only 64 MB ws)
        float* gbuf = (float*)ws;
        dim3 grid(2 * DIM / BNF, NROWS / BMF);
        sgemm_dual<<<grid, dim3(256), 0, stream>>>(X, Uw, Gw, out, gbuf);
        ladder_epilogue<<<dim3(NROWS), dim3(256), 0, stream>>>(X, gbuf, Lw, Vw, out);
    }
}

// Round 9
// 507.171 us; speedup vs baseline: 1.2233x; 1.2233x over previous
//
#include <hip/hip_runtime.h>
#include <cstdint>
#include <cstddef>

#define DIM 2048
#define NROWS 8192
#define NL 3
#define DEPTH 5
#define NLK 18            // NL*(DEPTH+1)
#define NCB 16            // col-blocks (DIM/128) contributing partials per row
#define CF_EPS 0.01f

// ---------------------------------------------------------------- MFMA GEMM
typedef __attribute__((ext_vector_type(8))) __bf16 bfrag;   // 8 bf16 = 4 VGPRs
typedef __attribute__((ext_vector_type(4))) float f32x4;

typedef __attribute__((address_space(1))) void gvoid;
typedef __attribute__((address_space(3))) void lvoid;

__device__ __forceinline__ void gld_lds16(const void* g, void* l) {
    // async global->LDS, 16B per lane, dest = wave-uniform base + lane*16
    __builtin_amdgcn_global_load_lds((gvoid*)g, (lvoid*)l, 16, 0, 0);
}

// ================================================================
// U GEMM + fused z*V^T epilogue:
//   out[r,c] = sum_k Xh[r,k]*Uwh[c,k]  +  z[r,0..2] . Vp[c,0..2]
// 128x128 tile, BK=32, 4 waves (2x2), 2-PHASE double-buffered LDS
// (2 x 16KB, one barrier per K-step): STAGE(t+1) issued BEFORE the
// compute on buf(t), so HBM latency hides under MFMA and the
// barrier's vmcnt(0) drain is short (round-4-proven loop pattern).
// ================================================================
__global__ __launch_bounds__(256) void mfma_gemm_u(
    const ushort* __restrict__ A, const ushort* __restrict__ B,
    const float* __restrict__ zb, const float* __restrict__ Vp,
    float* __restrict__ C)
{
    constexpr int BK = 32;
    constexpr int NT = DIM / BK;                 // 64 K-steps
    constexpr int TILE_E = 128 * BK;             // 4096 ushorts / tile
    constexpr int BUF_E  = 2 * TILE_E;           // A + B per buffer (16KB)
    __shared__ __align__(16) ushort smem_u[2 * BUF_E];   // 32KB

    const int tid  = threadIdx.x;
    const int wave = tid >> 6;
    const int lane = tid & 63;
    const int wm   = wave & 1;
    const int wn   = wave >> 1;
    const int m0   = blockIdx.y * 128;
    const int n0   = blockIdx.x * 128;

    // staging: wave w covers rows [w*32, w*32+32), lane -> row=lane>>2, chunk=lane&3
    const size_t soff = (size_t)(wave * 32 + (lane >> 2)) * DIM + (lane & 3) * 8;
    const ushort* gA = A + (size_t)m0 * DIM + soff;
    const ushort* gB = B + (size_t)n0 * DIM + soff;

    const int st0 = (wave * 32) * BK;            // within-tile dest offsets
    const int st1 = (wave * 32 + 16) * BK;

#define STAGE_U(K0S, BSEL)                                                     \
    {                                                                          \
        ushort* bp = smem_u + (BSEL) * BUF_E;                                  \
        gld_lds16(gA + (K0S), bp + st0);                                       \
        gld_lds16(gA + (size_t)16 * DIM + (K0S), bp + st1);                    \
        gld_lds16(gB + (K0S), bp + TILE_E + st0);                              \
        gld_lds16(gB + (size_t)16 * DIM + (K0S), bp + TILE_E + st1);           \
    }

    const int fm = lane & 15;
    const int fq = lane >> 4;

    f32x4 acc[4][4];
    #pragma unroll
    for (int i = 0; i < 4; ++i)
        #pragma unroll
        for (int j = 0; j < 4; ++j)
            acc[i][j] = (f32x4){0.f, 0.f, 0.f, 0.f};

    STAGE_U(0, 0)
    __syncthreads();                             // buf0 ready

    for (int t = 0; t < NT; ++t) {
        if (t + 1 < NT) STAGE_U((t + 1) * BK, (t + 1) & 1)   // async, early

        const ushort* bp = smem_u + (t & 1) * BUF_E;
        const ushort* pA = bp;
        const ushort* pB = bp + TILE_E;
        bfrag ah[4], bh[4];
        #pragma unroll
        for (int i = 0; i < 4; ++i) {
            ah[i] = *(const bfrag*)&pA[(wm * 64 + i * 16 + fm) * BK + fq * 8];
            bh[i] = *(const bfrag*)&pB[(wn * 64 + i * 16 + fm) * BK + fq * 8];
        }
        #pragma unroll
        for (int i = 0; i < 4; ++i)
            #pragma unroll
            for (int j = 0; j < 4; ++j)
                acc[i][j] = __builtin_amdgcn_mfma_f32_16x16x32_bf16(ah[i], bh[j], acc[i][j], 0, 0, 0);

        __syncthreads();   // drains STAGE(t+1) (issued one compute-phase ago)
    }
#undef STAGE_U

    // C/D layout: col = lane&15, row = (lane>>4)*4 + reg.  Fused: + z[row].V[col]
    float4 vc[4];
    #pragma unroll
    for (int j = 0; j < 4; ++j)
        vc[j] = *(const float4*)&Vp[(size_t)(n0 + wn * 64 + j * 16 + fm) * 4];

    #pragma unroll
    for (int i = 0; i < 4; ++i) {
        const int rowb = m0 + wm * 64 + i * 16 + fq * 4;
        #pragma unroll
        for (int r = 0; r < 4; ++r) {
            const float4 zr = *(const float4*)&zb[(size_t)(rowb + r) * 4];
            #pragma unroll
            for (int j = 0; j < 4; ++j) {
                const int col = n0 + wn * 64 + j * 16 + fm;
                C[(size_t)(rowb + r) * DIM + col] =
                    acc[i][j][r] + zr.x * vc[j].x + zr.y * vc[j].y + zr.z * vc[j].z;
            }
        }
    }
}

// ================================================================
// Gate GEMM (split-bf16, 3 MFMA chains) + fused gated-ladder reduction.
//   a_part[(row*NCB + cb)*NLK + lk] = sum_{c in tile} sig(g[r,c])*x[r,c]*Lw[lk,c]
// 2-PHASE double-buffered LDS (2 x 32KB = 64KB, one barrier/K-step,
// round-4-proven loop). Epilogue aliases buf0 (last compute reads
// buf1 since (NT-1)&1 == 1); quarter loop FULLY STATIC (rule #20).
// ================================================================
__global__ __launch_bounds__(256) void mfma_gemm_gate(
    const ushort* __restrict__ Ah, const ushort* __restrict__ Al,
    const ushort* __restrict__ Bh, const ushort* __restrict__ Bl,
    const float* __restrict__ X,  const float* __restrict__ Lw,
    float* __restrict__ a_part)
{
    constexpr int BK = 32;
    constexpr int NT = DIM / BK;                 // 64 K-steps
    constexpr int TILE_E = 128 * BK;             // 4096 ushorts / tile
    constexpr int BUF_E  = 4 * TILE_E;           // Ah,Bh,Al,Bl per buffer (32KB)
    __shared__ __align__(16) ushort smem_u[2 * BUF_E];   // 64KB
    float*  sG  = (float*)smem_u;                        // epilogue alias (buf0)
    float*  sLw = (float*)((char*)smem_u + 16896);

    const int tid  = threadIdx.x;
    const int wave = tid >> 6;
    const int lane = tid & 63;
    const int wm   = wave & 1;
    const int wn   = wave >> 1;
    const int m0   = blockIdx.y * 128;
    const int n0   = blockIdx.x * 128;

    const size_t soff = (size_t)(wave * 32 + (lane >> 2)) * DIM + (lane & 3) * 8;
    const ushort* gA  = Ah + (size_t)m0 * DIM + soff;
    const ushort* gAl = Al + (size_t)m0 * DIM + soff;
    const ushort* gB  = Bh + (size_t)n0 * DIM + soff;
    const ushort* gBl = Bl + (size_t)n0 * DIM + soff;

    const int st0 = (wave * 32) * BK;
    const int st1 = (wave * 32 + 16) * BK;

#define STAGE_G(K0S, BSEL)                                                     \
    {                                                                          \
        ushort* bp = smem_u + (BSEL) * BUF_E;                                  \
        gld_lds16(gA  + (K0S), bp + st0);                                      \
        gld_lds16(gA  + (size_t)16 * DIM + (K0S), bp + st1);                   \
        gld_lds16(gB  + (K0S), bp + TILE_E + st0);                             \
        gld_lds16(gB  + (size_t)16 * DIM + (K0S), bp + TILE_E + st1);          \
        gld_lds16(gAl + (K0S), bp + 2 * TILE_E + st0);                         \
        gld_lds16(gAl + (size_t)16 * DIM + (K0S), bp + 2 * TILE_E + st1);      \
        gld_lds16(gBl + (K0S), bp + 3 * TILE_E + st0);                         \
        gld_lds16(gBl + (size_t)16 * DIM + (K0S), bp + 3 * TILE_E + st1);      \
    }

    const int fm = lane & 15;
    const int fq = lane >> 4;

    f32x4 acc[4][4];
    #pragma unroll
    for (int i = 0; i < 4; ++i)
        #pragma unroll
        for (int j = 0; j < 4; ++j)
            acc[i][j] = (f32x4){0.f, 0.f, 0.f, 0.f};

    STAGE_G(0, 0)
    __syncthreads();                             // buf0 ready

    for (int t = 0; t < NT; ++t) {
        if (t + 1 < NT) STAGE_G((t + 1) * BK, (t + 1) & 1)   // async, early

        const ushort* bp  = smem_u + (t & 1) * BUF_E;
        const ushort* bAh = bp;
        const ushort* bBh = bp + TILE_E;
        const ushort* bAl = bp + 2 * TILE_E;
        const ushort* bBl = bp + 3 * TILE_E;

        bfrag ah[4], bh[4], al[4], bl[4];
        #pragma unroll
        for (int i = 0; i < 4; ++i) {
            ah[i] = *(const bfrag*)&bAh[(wm * 64 + i * 16 + fm) * BK + fq * 8];
            bh[i] = *(const bfrag*)&bBh[(wn * 64 + i * 16 + fm) * BK + fq * 8];
            al[i] = *(const bfrag*)&bAl[(wm * 64 + i * 16 + fm) * BK + fq * 8];
            bl[i] = *(const bfrag*)&bBl[(wn * 64 + i * 16 + fm) * BK + fq * 8];
        }
        #pragma unroll
        for (int i = 0; i < 4; ++i)
            #pragma unroll
            for (int j = 0; j < 4; ++j) {
                acc[i][j] = __builtin_amdgcn_mfma_f32_16x16x32_bf16(ah[i], bh[j], acc[i][j], 0, 0, 0);
                acc[i][j] = __builtin_amdgcn_mfma_f32_16x16x32_bf16(ah[i], bl[j], acc[i][j], 0, 0, 0);
                acc[i][j] = __builtin_amdgcn_mfma_f32_16x16x32_bf16(al[i], bh[j], acc[i][j], 0, 0, 0);
            }

        __syncthreads();   // drains STAGE(t+1); guards buf reads
    }
#undef STAGE_G

    // ---- fused gated-ladder reduction, four 32-row quarters (STATIC) ----
    const float* xblk = X + (size_t)m0 * DIM + n0;
    const int rred  = ((tid >> 6) << 3) | (tid & 7);   // reduce row 0..31
    const int strip = (lane >> 3) & 7;                 // 8 strips x 16 cols
    const int qc    = strip * 16;

#define DO_QUARTER(Q)                                                          \
    {                                                                          \
        __syncthreads();  /* previous-quarter reads done */                    \
        if (Q == 0) {                                                          \
            /* ladder weights, strip-swizzled (+4 dwords per 16-col strip) */  \
            for (int idx = tid; idx < NLK * 128; idx += 256) {                 \
                const int lk = idx >> 7, c = idx & 127;                        \
                sLw[lk * 156 + c + ((c >> 4) << 2)] = Lw[(size_t)lk * DIM + n0 + c]; \
            }                                                                  \
        }                                                                      \
        if (wm == (Q >> 1)) {                                                  \
            constexpr int ib = (Q & 1) * 2;  /* compile-time: keeps acc in VGPRs */ \
            _Pragma("unroll")                                                  \
            for (int ii = 0; ii < 2; ++ii) {                                   \
                _Pragma("unroll")                                              \
                for (int r = 0; r < 4; ++r) {                                  \
                    const int rloc = ii * 16 + fq * 4 + r;      /* 0..31 */    \
                    const float* xr = xblk + (size_t)(Q * 32 + rloc) * DIM;    \
                    _Pragma("unroll")                                          \
                    for (int j = 0; j < 4; ++j) {                              \
                        const int cc = wn * 64 + j * 16 + fm;                  \
                        const float g = acc[ib + ii][j][r];                    \
                        const float s = 1.0f / (1.0f + __expf(-g));            \
                        sG[rloc * 132 + cc] = s * xr[cc];                      \
                    }                                                          \
                }                                                              \
            }                                                                  \
        }                                                                      \
        __syncthreads();   /* sG (+ sLw at Q==0) ready */                      \
        float p[NLK];                                                          \
        _Pragma("unroll")                                                      \
        for (int lk = 0; lk < NLK; ++lk) p[lk] = 0.f;                          \
        _Pragma("unroll")                                                      \
        for (int c4 = 0; c4 < 16; c4 += 4) {                                   \
            const float4 g4 = *(const float4*)&sG[rred * 132 + qc + c4];       \
            _Pragma("unroll")                                                  \
            for (int lk = 0; lk < NLK; ++lk) {                                 \
                const float4 w4 = *(const float4*)&sLw[lk * 156 + qc + c4 + (strip << 2)]; \
                p[lk] = fmaf(g4.x, w4.x, fmaf(g4.y, w4.y,                      \
                        fmaf(g4.z, w4.z, fmaf(g4.w, w4.w, p[lk]))));           \
            }                                                                  \
        }                                                                      \
        _Pragma("unroll")                                                      \
        for (int lk = 0; lk < NLK; ++lk) {                                     \
            p[lk] += __shfl_xor(p[lk], 8, 64);                                 \
            p[lk] += __shfl_xor(p[lk], 16, 64);                                \
            p[lk] += __shfl_xor(p[lk], 32, 64);                                \
        }                                                                      \
        if ((lane >> 3) == 0) {                                                \
            float* dst = a_part +                                              \
                ((size_t)(m0 + Q * 32 + rred) * NCB + blockIdx.x) * NLK;       \
            _Pragma("unroll")                                                  \
            for (int lk = 0; lk < NLK; ++lk) dst[lk] = p[lk];                  \
        }                                                                      \
    }

    DO_QUARTER(0)
    DO_QUARTER(1)
    DO_QUARTER(2)
    DO_QUARTER(3)
#undef DO_QUARTER
}

// ================================================================
// reduce partials + continued fraction:
//   a_part[8192][NCB][18] -> z_buf[8192][4]
// ================================================================
__global__ __launch_bounds__(256) void cf_kernel(const float* __restrict__ a_part,
                                                 float* __restrict__ zb)
{
    const int r = blockIdx.x * 256 + threadIdx.x;
    const float* ap = a_part + (size_t)r * NCB * NLK;
    float a[NLK];
    #pragma unroll
    for (int lk = 0; lk < NLK; ++lk) a[lk] = 0.f;
    #pragma unroll 4
    for (int cb = 0; cb < NCB; ++cb) {
        #pragma unroll
        for (int lk = 0; lk < NLK; ++lk)
            a[lk] += ap[cb * NLK + lk];
    }
    float z[NL];
    #pragma unroll
    for (int l = 0; l < NL; ++l) {
        float f = 0.f;
        #pragma unroll
        for (int k = DEPTH - 1; k >= 0; --k) {
            float denom = 1.f + f;
            if (fabsf(denom) < CF_EPS) denom = (denom >= 0.f) ? CF_EPS : -CF_EPS;
            f = a[l * (DEPTH + 1) + k + 1] / denom;
        }
        z[l] = a[l * (DEPTH + 1)] + f;
    }
    *(float4*)&zb[(size_t)r * 4] = make_float4(z[0], z[1], z[2], 0.f);
}

// V_w [2048][3] -> padded [2048][4] for aligned float4 loads
__global__ __launch_bounds__(256) void padV(const float* __restrict__ Vw,
                                            float* __restrict__ Vp)
{
    const int d = blockIdx.x * 256 + threadIdx.x;
    *(float4*)&Vp[(size_t)d * 4] =
        make_float4(Vw[(size_t)d * 3], Vw[(size_t)d * 3 + 1], Vw[(size_t)d * 3 + 2], 0.f);
}

// ---------------------------------------------------------------- prep
__device__ __forceinline__ ushort f2bf_bits(float f) {
    __bf16 h = (__bf16)f;                        // RNE
    return __builtin_bit_cast(unsigned short, h);
}
__device__ __forceinline__ float bfbits2f(ushort u) {
    __bf16 h = __builtin_bit_cast(__bf16, u);
    return (float)h;
}

union U16x8 { ushort u[8]; uint4 v; };

__global__ __launch_bounds__(256) void split2(const float* __restrict__ src,
                                              ushort* __restrict__ hi,
                                              ushort* __restrict__ lo)
{
    const size_t i0 = ((size_t)blockIdx.x * 256 + threadIdx.x) * 8;
    const float4 v0 = *(const float4*)(src + i0);
    const float4 v1 = *(const float4*)(src + i0 + 4);
    const float f[8] = {v0.x, v0.y, v0.z, v0.w, v1.x, v1.y, v1.z, v1.w};
    U16x8 h, l;
    #pragma unroll
    for (int j = 0; j < 8; ++j) {
        const ushort hb = f2bf_bits(f[j]);
        h.u[j] = hb;
        l.u[j] = f2bf_bits(f[j] - bfbits2f(hb));
    }
    *(uint4*)(hi + i0) = h.v;
    *(uint4*)(lo + i0) = l.v;
}

__global__ __launch_bounds__(256) void tobf16(const float* __restrict__ src,
                                              ushort* __restrict__ dst)
{
    const size_t i0 = ((size_t)blockIdx.x * 256 + threadIdx.x) * 8;
    const float4 v0 = *(const float4*)(src + i0);
    const float4 v1 = *(const float4*)(src + i0 + 4);
    const float f[8] = {v0.x, v0.y, v0.z, v0.w, v1.x, v1.y, v1.z, v1.w};
    U16x8 h;
    #pragma unroll
    for (int j = 0; j < 8; ++j) h.u[j] = f2bf_bits(f[j]);
    *(uint4*)(dst + i0) = h.v;
}

// ---------------------------------------------------------------- fp32 fallback GEMM (round-1, proven)
#define BMF 128
#define BNF 128
#define BKF 16
#define LDAF 132

__global__ __launch_bounds__(256) void sgemm_dual(
    const float* __restrict__ X,
    const float* __restrict__ Uw,
    const float* __restrict__ Gw,
    float* __restrict__ outLin,
    float* __restrict__ outGate)
{
    __shared__ float As[BKF][LDAF];
    __shared__ float Bs[BKF][LDAF];

    const int tid = threadIdx.x;
    const int n0 = blockIdx.x * BNF;
    const int m0 = blockIdx.y * BMF;
    const bool isGate = (n0 >= DIM);
    const float* W = isGate ? Gw : Uw;
    float* C = isGate ? outGate : outLin;
    const int nb = isGate ? (n0 - DIM) : n0;

    const int lr = tid >> 2;
    const int lc = (tid & 3) << 2;

    const float* pa0 = X + (size_t)(m0 + lr) * DIM + lc;
    const float* pa1 = X + (size_t)(m0 + lr + 64) * DIM + lc;
    const float* pb0 = W + (size_t)(nb + lr) * DIM + lc;
    const float* pb1 = W + (size_t)(nb + lr + 64) * DIM + lc;

    const int tx = tid & 15;
    const int ty = tid >> 4;

    float acc[8][8];
    #pragma unroll
    for (int i = 0; i < 8; ++i)
        #pragma unroll
        for (int j = 0; j < 8; ++j) acc[i][j] = 0.f;

    for (int k0 = 0; k0 < DIM; k0 += BKF) {
        const float4 a0 = *(const float4*)(pa0 + k0);
        const float4 a1 = *(const float4*)(pa1 + k0);
        const float4 b0 = *(const float4*)(pb0 + k0);
        const float4 b1 = *(const float4*)(pb1 + k0);
        __syncthreads();
        As[lc + 0][lr] = a0.x; As[lc + 1][lr] = a0.y; As[lc + 2][lr] = a0.z; As[lc + 3][lr] = a0.w;
        As[lc + 0][lr + 64] = a1.x; As[lc + 1][lr + 64] = a1.y; As[lc + 2][lr + 64] = a1.z; As[lc + 3][lr + 64] = a1.w;
        Bs[lc + 0][lr] = b0.x; Bs[lc + 1][lr] = b0.y; Bs[lc + 2][lr] = b0.z; Bs[lc + 3][lr] = b0.w;
        Bs[lc + 0][lr + 64] = b1.x; Bs[lc + 1][lr + 64] = b1.y; Bs[lc + 2][lr + 64] = b1.z; Bs[lc + 3][lr + 64] = b1.w;
        __syncthreads();
        #pragma unroll
        for (int kk = 0; kk < BKF; ++kk) {
            float av[8], bv[8];
            *(float4*)&av[0] = *(const float4*)&As[kk][ty * 8];
            *(float4*)&av[4] = *(const float4*)&As[kk][ty * 8 + 4];
            *(float4*)&bv[0] = *(const float4*)&Bs[kk][tx * 8];
            *(float4*)&bv[4] = *(const float4*)&Bs[kk][tx * 8 + 4];
            #pragma unroll
            for (int i = 0; i < 8; ++i)
                #pragma unroll
                for (int j = 0; j < 8; ++j)
                    acc[i][j] = fmaf(av[i], bv[j], acc[i][j]);
        }
    }

    #pragma unroll
    for (int i = 0; i < 8; ++i) {
        float* crow = C + (size_t)(m0 + ty * 8 + i) * DIM + nb + tx * 8;
        *(float4*)crow       = make_float4(acc[i][0], acc[i][1], acc[i][2], acc[i][3]);
        *(float4*)(crow + 4) = make_float4(acc[i][4], acc[i][5], acc[i][6], acc[i][7]);
    }
}

// ---------------------------------------------------------------- epilogue (fallback path only)
__global__ __launch_bounds__(256) void ladder_epilogue(
    const float* __restrict__ X,
    const float* __restrict__ G,
    const float* __restrict__ Lw,
    const float* __restrict__ Vw,
    float* __restrict__ Out)
{
    const int r = blockIdx.x;
    const int tid = threadIdx.x;
    const int d0 = tid * 8;
    const float* xrow = X + (size_t)r * DIM;
    const float* grow = G + (size_t)r * DIM;

    const float4 xv0 = *(const float4*)(xrow + d0);
    const float4 xv1 = *(const float4*)(xrow + d0 + 4);
    const float4 gv0 = *(const float4*)(grow + d0);
    const float4 gv1 = *(const float4*)(grow + d0 + 4);

    float gated[8];
    {
        const float gx[8] = {gv0.x, gv0.y, gv0.z, gv0.w, gv1.x, gv1.y, gv1.z, gv1.w};
        const float xx[8] = {xv0.x, xv0.y, xv0.z, xv0.w, xv1.x, xv1.y, xv1.z, xv1.w};
        #pragma unroll
        for (int j = 0; j < 8; ++j) {
            const float s = 1.0f / (1.0f + __expf(-gx[j]));
            gated[j] = s * xx[j];
        }
    }

    float part[NLK];
    #pragma unroll
    for (int lk = 0; lk < NLK; ++lk) {
        const float* lrow = Lw + (size_t)lk * DIM + d0;
        const float4 w0 = *(const float4*)lrow;
        const float4 w1 = *(const float4*)(lrow + 4);
        part[lk] = gated[0] * w0.x + gated[1] * w0.y + gated[2] * w0.z + gated[3] * w0.w
                 + gated[4] * w1.x + gated[5] * w1.y + gated[6] * w1.z + gated[7] * w1.w;
    }

    #pragma unroll
    for (int off = 32; off > 0; off >>= 1) {
        #pragma unroll
        for (int lk = 0; lk < NLK; ++lk)
            part[lk] += __shfl_down(part[lk], off, 64);
    }

    __shared__ float red[4][NLK];
    __shared__ float zsh[NL];
    const int wave = tid >> 6;
    const int lane = tid & 63;
    if (lane == 0) {
        #pragma unroll
        for (int lk = 0; lk < NLK; ++lk) red[wave][lk] = part[lk];
    }
    __syncthreads();
    if (tid < NL) {
        float a[DEPTH + 1];
        #pragma unroll
        for (int k = 0; k < DEPTH + 1; ++k)
            a[k] = red[0][tid * 6 + k] + red[1][tid * 6 + k]
                 + red[2][tid * 6 + k] + red[3][tid * 6 + k];
        float f = 0.f;
        #pragma unroll
        for (int k = DEPTH - 1; k >= 0; --k) {
            float denom = 1.f + f;
            if (fabsf(denom) < CF_EPS) denom = (denom >= 0.f) ? CF_EPS : -CF_EPS;
            f = a[k + 1] / denom;
        }
        zsh[tid] = a[0] + f;
    }
    __syncthreads();
    const float z0 = zsh[0], z1 = zsh[1], z2 = zsh[2];

    float* orow = Out + (size_t)r * DIM + d0;
    const float4 o0 = *(const float4*)orow;
    const float4 o1 = *(const float4*)(orow + 4);
    float ov[8] = {o0.x, o0.y, o0.z, o0.w, o1.x, o1.y, o1.z, o1.w};
    #pragma unroll
    for (int j = 0; j < 8; ++j) {
        const float* vp = Vw + (size_t)(d0 + j) * NL;
        ov[j] += z0 * vp[0] + z1 * vp[1] + z2 * vp[2];
    }
    *(float4*)orow       = make_float4(ov[0], ov[1], ov[2], ov[3]);
    *(float4*)(orow + 4) = make_float4(ov[4], ov[5], ov[6], ov[7]);
}

// ---------------------------------------------------------------- launch
extern "C" void kernel_launch(void* const* d_in, const int* in_sizes, int n_in,
                              void* d_out, int out_size, void* d_ws, size_t ws_size,
                              hipStream_t stream) {
    const float* X  = (const float*)d_in[0];
    const float* Uw = (const float*)d_in[1];
    const float* Gw = (const float*)d_in[2];
    const float* Lw = (const float*)d_in[3];
    const float* Vw = (const float*)d_in[4];
    float* out = (float*)d_out;

    // ws layout (bytes):
    //   Xh  bf16    @ 0           33554432
    //   Xl  bf16    @ 33554432    33554432
    //   Gwh bf16    @ 67108864     8388608
    //   Gwl bf16    @ 75497472     8388608
    //   Uwh bf16    @ 83886080     8388608
    //   a_part f32  @ 92274688     9437184   (8192 x 16 x 18)
    //   z_buf f32   @ 101711872     131072   (8192 x 4)
    //   Vp  f32     @ 101842944      32768   (2048 x 4)
    const size_t WS_NEED = 101875712ull;
    char* ws = (char*)d_ws;

    if (ws_size >= WS_NEED) {
        ushort* Xh     = (ushort*)(ws);
        ushort* Xl     = (ushort*)(ws + 33554432);
        ushort* Gwh    = (ushort*)(ws + 67108864);
        ushort* Gwl    = (ushort*)(ws + 75497472);
        ushort* Uwh    = (ushort*)(ws + 83886080);
        float*  a_part = (float*)(ws + 92274688);
        float*  z_buf  = (float*)(ws + 101711872);
        float*  Vp     = (float*)(ws + 101842944);

        split2<<<dim3(8192), dim3(256), 0, stream>>>(X, Xh, Xl);       // 16.78M elems
        split2<<<dim3(2048), dim3(256), 0, stream>>>(Gw, Gwh, Gwl);    // 4.19M elems
        tobf16<<<dim3(2048), dim3(256), 0, stream>>>(Uw, Uwh);
        padV  <<<dim3(8),    dim3(256), 0, stream>>>(Vw, Vp);

        dim3 grid(DIM / 128, NROWS / 128);   // (16, 64)
        mfma_gemm_gate<<<grid, dim3(256), 0, stream>>>(Xh, Xl, Gwh, Gwl, X, Lw, a_part);
        cf_kernel<<<dim3(32), dim3(256), 0, stream>>>(a_part, z_buf);
        mfma_gemm_u<<<grid, dim3(256), 0, stream>>>(Xh, Uwh, z_buf, Vp, out);
    } else {
        // fallback: round-1 fp32 path (needs only 64 MB ws)
        float* gbuf = (float*)ws;
        dim3 grid(2 * DIM / BNF, NROWS / BMF);
        sgemm_dual<<<grid, dim3(256), 0, stream>>>(X, Uw, Gw, out, gbuf);
        ladder_epilogue<<<dim3(NROWS), dim3(256), 0, stream>>>(X, gbuf, Lw, Vw, out);
    }
}

// Round 10
// 498.699 us; speedup vs baseline: 1.2441x; 1.0170x over previous
//
#include <hip/hip_runtime.h>
#include <cstdint>
#include <cstddef>

#define DIM 2048
#define NROWS 8192
#define NL 3
#define DEPTH 5
#define NLK 18            // NL*(DEPTH+1)
#define NCB 16            // col-blocks (DIM/128) contributing partials per row
#define CF_EPS 0.01f

// ---------------------------------------------------------------- MFMA GEMM
typedef __attribute__((ext_vector_type(8))) __bf16 bfrag;   // 8 bf16 = 4 VGPRs
typedef __attribute__((ext_vector_type(4))) float f32x4;

typedef __attribute__((address_space(1))) void gvoid;
typedef __attribute__((address_space(3))) void lvoid;

__device__ __forceinline__ void gld_lds16(const void* g, void* l) {
    // async global->LDS, 16B per lane, dest = wave-uniform base + lane*16
    __builtin_amdgcn_global_load_lds((gvoid*)g, (lvoid*)l, 16, 0, 0);
}

// ================================================================
// FUSED, WAVE-SPECIALIZED GEMM (512 thr = 8 waves) — round-4 kernel,
// MEASURED 357us (vs 440us serial gate+U):
//   waves 0-3: gate tile g = split-bf16 (3-chain) Xh/Xl x Gwh/Gwl  (48 MFMA/step)
//   waves 4-7: U tile    out = Xh x Uwh (raw; z*V^T added by zv_add)
// Both groups use THE SAME acc[4][4] (VGPR 92, no spill).
// Double-buffered LDS (2 x 5 x 8KB = 80KB), ONE barrier per K-step.
// Gate epilogue: in-block gated-ladder reduction -> a_part.
// FULLY STATIC quarter loop (rule #20).
// ================================================================
__global__ __launch_bounds__(512, 2) void mfma_gemm_fused(
    const ushort* __restrict__ Xh, const ushort* __restrict__ Xl,
    const ushort* __restrict__ Gwh, const ushort* __restrict__ Gwl,
    const ushort* __restrict__ Uwh,
    const float* __restrict__ X,  const float* __restrict__ Lw,
    float* __restrict__ outU, float* __restrict__ a_part)
{
    constexpr int BK = 32;
    constexpr int NT = DIM / BK;            // 64 K-steps
    constexpr int TILE_E = 4096;            // ushorts per 128x32 tile (8KB)
    constexpr int BUF_E  = 5 * TILE_E;      // 20480 ushorts per buffer
    // [0, 81920): 2 x (Xh,Xl,Gh,Gl,Uh) staging buffers
    // epilogue aliases buf0: sG [0,16896) = 32x132 f32 ; sLw [16896,28128)
    __shared__ __align__(16) char smem[2 * 5 * 8192];
    ushort* smem_u = (ushort*)smem;
    float*  sG  = (float*)(smem);
    float*  sLw = (float*)(smem + 16896);

    const int tid  = threadIdx.x;
    const int wave = tid >> 6;
    const int lane = tid & 63;
    const int w2   = wave & 3;              // index within group
    const int wm   = w2 & 1;
    const int wn   = w2 >> 1;
    const bool isGate = (wave < 4);
    const int m0   = blockIdx.y * 128;
    const int n0   = blockIdx.x * 128;

    // ---- staging slots: 5 tiles x 8 chunks(16 rows) = 40 gld / K-step,
    // 5 per wave; computed ONCE into named vars (no runtime arrays).
    const ushort* src0; const ushort* src1; const ushort* src2;
    const ushort* src3; const ushort* src4;
    int doff0, doff1, doff2, doff3, doff4;
    {
        const int lrow = lane >> 2, lcol = (lane & 3) * 8;
#define SLOT_INIT(C, SRC, DOFF)                                                \
        {                                                                      \
            const int s  = wave * 5 + (C);                                     \
            const int t  = s >> 3, ch = s & 7;                                 \
            const ushort* base = (t == 0) ? Xh : (t == 1) ? Xl :               \
                                 (t == 2) ? Gwh : (t == 3) ? Gwl : Uwh;        \
            const int rb = (t < 2) ? m0 : n0;                                  \
            SRC  = base + (size_t)(rb + ch * 16 + lrow) * DIM + lcol;          \
            DOFF = t * TILE_E + ch * 512;   /* 16 rows x 32 ushorts */         \
        }
        SLOT_INIT(0, src0, doff0)
        SLOT_INIT(1, src1, doff1)
        SLOT_INIT(2, src2, doff2)
        SLOT_INIT(3, src3, doff3)
        SLOT_INIT(4, src4, doff4)
#undef SLOT_INIT
    }

#define STAGE(K0S, BSEL)                                                       \
    {                                                                          \
        ushort* bp = smem_u + (BSEL) * BUF_E;                                  \
        gld_lds16(src0 + (K0S), bp + doff0);                                   \
        gld_lds16(src1 + (K0S), bp + doff1);                                   \
        gld_lds16(src2 + (K0S), bp + doff2);                                   \
        gld_lds16(src3 + (K0S), bp + doff3);                                   \
        gld_lds16(src4 + (K0S), bp + doff4);                                   \
    }

    const int fm = lane & 15;
    const int fq = lane >> 4;

    f32x4 acc[4][4];                        // gate logits OR U output
    #pragma unroll
    for (int i = 0; i < 4; ++i)
        #pragma unroll
        for (int j = 0; j < 4; ++j)
            acc[i][j] = (f32x4){0.f, 0.f, 0.f, 0.f};

    STAGE(0, 0)
    __syncthreads();                        // buf0 ready

    #pragma unroll 2
    for (int t = 0; t < NT; ++t) {
        if (t + 1 < NT) STAGE((t + 1) * BK, (t + 1) & 1)   // async into other buf

        const ushort* bb  = smem_u + (t & 1) * BUF_E;
        const ushort* bXh = bb;
        const ushort* bXl = bb + TILE_E;
        const ushort* bGh = bb + 2 * TILE_E;
        const ushort* bGl = bb + 3 * TILE_E;
        const ushort* bUh = bb + 4 * TILE_E;

        if (isGate) {
            bfrag ah[4], al[4];
            #pragma unroll
            for (int i = 0; i < 4; ++i) {
                ah[i] = *(const bfrag*)&bXh[(wm * 64 + i * 16 + fm) * BK + fq * 8];
                al[i] = *(const bfrag*)&bXl[(wm * 64 + i * 16 + fm) * BK + fq * 8];
            }
            #pragma unroll
            for (int j = 0; j < 4; ++j) {
                const bfrag bh = *(const bfrag*)&bGh[(wn * 64 + j * 16 + fm) * BK + fq * 8];
                const bfrag bl = *(const bfrag*)&bGl[(wn * 64 + j * 16 + fm) * BK + fq * 8];
                #pragma unroll
                for (int i = 0; i < 4; ++i) {
                    acc[i][j] = __builtin_amdgcn_mfma_f32_16x16x32_bf16(ah[i], bh, acc[i][j], 0, 0, 0);
                    acc[i][j] = __builtin_amdgcn_mfma_f32_16x16x32_bf16(ah[i], bl, acc[i][j], 0, 0, 0);
                    acc[i][j] = __builtin_amdgcn_mfma_f32_16x16x32_bf16(al[i], bh, acc[i][j], 0, 0, 0);
                }
            }
        } else {
            bfrag ah[4];
            #pragma unroll
            for (int i = 0; i < 4; ++i)
                ah[i] = *(const bfrag*)&bXh[(wm * 64 + i * 16 + fm) * BK + fq * 8];
            #pragma unroll
            for (int j = 0; j < 4; ++j) {
                const bfrag bu = *(const bfrag*)&bUh[(wn * 64 + j * 16 + fm) * BK + fq * 8];
                #pragma unroll
                for (int i = 0; i < 4; ++i)
                    acc[i][j] = __builtin_amdgcn_mfma_f32_16x16x32_bf16(ah[i], bu, acc[i][j], 0, 0, 0);
            }
        }
        __syncthreads();   // staging of t+1 drained; buf[t&1] reads done
    }
#undef STAGE

    // ---- U waves: write C tile (stores fly during gate epilogue) ----
    // C/D layout: col = lane&15, row = (lane>>4)*4 + reg
    if (!isGate) {
        #pragma unroll
        for (int i = 0; i < 4; ++i) {
            const int rowb = m0 + wm * 64 + i * 16 + fq * 4;
            #pragma unroll
            for (int j = 0; j < 4; ++j) {
                const int col = n0 + wn * 64 + j * 16 + fm;
                #pragma unroll
                for (int r = 0; r < 4; ++r)
                    outU[(size_t)(rowb + r) * DIM + col] = acc[i][j][r];
            }
        }
    }

    // ---- gate epilogue: gated-ladder reduction, 4 x 32-row quarters (STATIC) ----
    const float* xblk = X + (size_t)m0 * DIM + n0;
    const int rred  = ((tid >> 6) << 3) | (tid & 7);   // (gate waves) row 0..31
    const int strip = (lane >> 3) & 7;                 // 8 strips x 16 cols
    const int qc    = strip * 16;

#define DO_QUARTER(Q)                                                          \
    {                                                                          \
        __syncthreads();  /* staging/reads of prev quarter done */             \
        if (Q == 0) {                                                          \
            /* ladder weights, strip-swizzled (+4 dwords per 16-col strip) */  \
            for (int idx = tid; idx < NLK * 128; idx += 512) {                 \
                const int lk = idx >> 7, c = idx & 127;                        \
                sLw[lk * 156 + c + ((c >> 4) << 2)] = Lw[(size_t)lk * DIM + n0 + c]; \
            }                                                                  \
        }                                                                      \
        if (isGate && wm == (Q >> 1)) {                                        \
            constexpr int ib = (Q & 1) * 2;  /* compile-time acc index */      \
            _Pragma("unroll")                                                  \
            for (int ii = 0; ii < 2; ++ii) {                                   \
                _Pragma("unroll")                                              \
                for (int r = 0; r < 4; ++r) {                                  \
                    const int rloc = ii * 16 + fq * 4 + r;      /* 0..31 */    \
                    const float* xr = xblk + (size_t)(Q * 32 + rloc) * DIM;    \
                    _Pragma("unroll")                                          \
                    for (int j = 0; j < 4; ++j) {                              \
                        const int cc = wn * 64 + j * 16 + fm;                  \
                        const float g = acc[ib + ii][j][r];                    \
                        const float s = 1.0f / (1.0f + __expf(-g));            \
                        sG[rloc * 132 + cc] = s * xr[cc];                      \
                    }                                                          \
                }                                                              \
            }                                                                  \
        }                                                                      \
        __syncthreads();   /* sG (+ sLw at Q==0) ready */                      \
        if (isGate) {                                                          \
            float p[NLK];                                                      \
            _Pragma("unroll")                                                  \
            for (int lk = 0; lk < NLK; ++lk) p[lk] = 0.f;                      \
            _Pragma("unroll")                                                  \
            for (int c4 = 0; c4 < 16; c4 += 4) {                               \
                const float4 g4 = *(const float4*)&sG[rred * 132 + qc + c4];   \
                _Pragma("unroll")                                              \
                for (int lk = 0; lk < NLK; ++lk) {                             \
                    const float4 w4 = *(const float4*)&sLw[lk * 156 + qc + c4 + (strip << 2)]; \
                    p[lk] = fmaf(g4.x, w4.x, fmaf(g4.y, w4.y,                  \
                            fmaf(g4.z, w4.z, fmaf(g4.w, w4.w, p[lk]))));       \
                }                                                              \
            }                                                                  \
            _Pragma("unroll")                                                  \
            for (int lk = 0; lk < NLK; ++lk) {                                 \
                p[lk] += __shfl_xor(p[lk], 8, 64);                             \
                p[lk] += __shfl_xor(p[lk], 16, 64);                            \
                p[lk] += __shfl_xor(p[lk], 32, 64);                            \
            }                                                                  \
            if ((lane >> 3) == 0) {                                            \
                float* dst = a_part +                                          \
                    ((size_t)(m0 + Q * 32 + rred) * NCB + blockIdx.x) * NLK;   \
                _Pragma("unroll")                                              \
                for (int lk = 0; lk < NLK; ++lk) dst[lk] = p[lk];              \
            }                                                                  \
        }                                                                      \
    }

    DO_QUARTER(0)
    DO_QUARTER(1)
    DO_QUARTER(2)
    DO_QUARTER(3)
#undef DO_QUARTER
}

// ================================================================
// reduce partials + continued fraction:
//   a_part[8192][NCB][18] -> z_buf[8192][4]     (round-5-proven)
// ================================================================
__global__ __launch_bounds__(256) void cf_kernel(const float* __restrict__ a_part,
                                                 float* __restrict__ zb)
{
    const int r = blockIdx.x * 256 + threadIdx.x;
    const float* ap = a_part + (size_t)r * NCB * NLK;
    float a[NLK];
    #pragma unroll
    for (int lk = 0; lk < NLK; ++lk) a[lk] = 0.f;
    #pragma unroll 4
    for (int cb = 0; cb < NCB; ++cb) {
        #pragma unroll
        for (int lk = 0; lk < NLK; ++lk)
            a[lk] += ap[cb * NLK + lk];
    }
    float z[NL];
    #pragma unroll
    for (int l = 0; l < NL; ++l) {
        float f = 0.f;
        #pragma unroll
        for (int k = DEPTH - 1; k >= 0; --k) {
            float denom = 1.f + f;
            if (fabsf(denom) < CF_EPS) denom = (denom >= 0.f) ? CF_EPS : -CF_EPS;
            f = a[l * (DEPTH + 1) + k + 1] / denom;
        }
        z[l] = a[l * (DEPTH + 1)] + f;
    }
    *(float4*)&zb[(size_t)r * 4] = make_float4(z[0], z[1], z[2], 0.f);
}

// ================================================================
// out[r,:] += z[r] . Vw[:,0..2]   (coalesced RMW; Vw read direct,
// 96B contiguous per thread, L2-resident 24KB)
// ================================================================
__global__ __launch_bounds__(256) void zv_add(
    float* __restrict__ out, const float* __restrict__ zb,
    const float* __restrict__ Vw)
{
    const int r  = blockIdx.x;
    const int c0 = threadIdx.x * 8;
    const float4 z = *(const float4*)&zb[(size_t)r * 4];
    float* orow = out + (size_t)r * DIM + c0;
    const float4 o0 = *(const float4*)orow;
    const float4 o1 = *(const float4*)(orow + 4);
    float ov[8] = {o0.x, o0.y, o0.z, o0.w, o1.x, o1.y, o1.z, o1.w};
    #pragma unroll
    for (int j = 0; j < 8; ++j) {
        const float* vp = Vw + (size_t)(c0 + j) * NL;
        ov[j] += z.x * vp[0] + z.y * vp[1] + z.z * vp[2];
    }
    *(float4*)orow       = make_float4(ov[0], ov[1], ov[2], ov[3]);
    *(float4*)(orow + 4) = make_float4(ov[4], ov[5], ov[6], ov[7]);
}

// ---------------------------------------------------------------- prep
__device__ __forceinline__ ushort f2bf_bits(float f) {
    __bf16 h = (__bf16)f;                        // RNE
    return __builtin_bit_cast(unsigned short, h);
}
__device__ __forceinline__ float bfbits2f(ushort u) {
    __bf16 h = __builtin_bit_cast(__bf16, u);
    return (float)h;
}

union U16x8 { ushort u[8]; uint4 v; };

__global__ __launch_bounds__(256) void split2(const float* __restrict__ src,
                                              ushort* __restrict__ hi,
                                              ushort* __restrict__ lo)
{
    const size_t i0 = ((size_t)blockIdx.x * 256 + threadIdx.x) * 8;
    const float4 v0 = *(const float4*)(src + i0);
    const float4 v1 = *(const float4*)(src + i0 + 4);
    const float f[8] = {v0.x, v0.y, v0.z, v0.w, v1.x, v1.y, v1.z, v1.w};
    U16x8 h, l;
    #pragma unroll
    for (int j = 0; j < 8; ++j) {
        const ushort hb = f2bf_bits(f[j]);
        h.u[j] = hb;
        l.u[j] = f2bf_bits(f[j] - bfbits2f(hb));
    }
    *(uint4*)(hi + i0) = h.v;
    *(uint4*)(lo + i0) = l.v;
}

__global__ __launch_bounds__(256) void tobf16(const float* __restrict__ src,
                                              ushort* __restrict__ dst)
{
    const size_t i0 = ((size_t)blockIdx.x * 256 + threadIdx.x) * 8;
    const float4 v0 = *(const float4*)(src + i0);
    const float4 v1 = *(const float4*)(src + i0 + 4);
    const float f[8] = {v0.x, v0.y, v0.z, v0.w, v1.x, v1.y, v1.z, v1.w};
    U16x8 h;
    #pragma unroll
    for (int j = 0; j < 8; ++j) h.u[j] = f2bf_bits(f[j]);
    *(uint4*)(dst + i0) = h.v;
}

// ---------------------------------------------------------------- fp32 fallback GEMM (round-1, proven)
#define BMF 128
#define BNF 128
#define BKF 16
#define LDAF 132

__global__ __launch_bounds__(256) void sgemm_dual(
    const float* __restrict__ X,
    const float* __restrict__ Uw,
    const float* __restrict__ Gw,
    float* __restrict__ outLin,
    float* __restrict__ outGate)
{
    __shared__ float As[BKF][LDAF];
    __shared__ float Bs[BKF][LDAF];

    const int tid = threadIdx.x;
    const int n0 = blockIdx.x * BNF;
    const int m0 = blockIdx.y * BMF;
    const bool isGate = (n0 >= DIM);
    const float* W = isGate ? Gw : Uw;
    float* C = isGate ? outGate : outLin;
    const int nb = isGate ? (n0 - DIM) : n0;

    const int lr = tid >> 2;
    const int lc = (tid & 3) << 2;

    const float* pa0 = X + (size_t)(m0 + lr) * DIM + lc;
    const float* pa1 = X + (size_t)(m0 + lr + 64) * DIM + lc;
    const float* pb0 = W + (size_t)(nb + lr) * DIM + lc;
    const float* pb1 = W + (size_t)(nb + lr + 64) * DIM + lc;

    const int tx = tid & 15;
    const int ty = tid >> 4;

    float acc[8][8];
    #pragma unroll
    for (int i = 0; i < 8; ++i)
        #pragma unroll
        for (int j = 0; j < 8; ++j) acc[i][j] = 0.f;

    for (int k0 = 0; k0 < DIM; k0 += BKF) {
        const float4 a0 = *(const float4*)(pa0 + k0);
        const float4 a1 = *(const float4*)(pa1 + k0);
        const float4 b0 = *(const float4*)(pb0 + k0);
        const float4 b1 = *(const float4*)(pb1 + k0);
        __syncthreads();
        As[lc + 0][lr] = a0.x; As[lc + 1][lr] = a0.y; As[lc + 2][lr] = a0.z; As[lc + 3][lr] = a0.w;
        As[lc + 0][lr + 64] = a1.x; As[lc + 1][lr + 64] = a1.y; As[lc + 2][lr + 64] = a1.z; As[lc + 3][lr + 64] = a1.w;
        Bs[lc + 0][lr] = b0.x; Bs[lc + 1][lr] = b0.y; Bs[lc + 2][lr] = b0.z; Bs[lc + 3][lr] = b0.w;
        Bs[lc + 0][lr + 64] = b1.x; Bs[lc + 1][lr + 64] = b1.y; Bs[lc + 2][lr + 64] = b1.z; Bs[lc + 3][lr + 64] = b1.w;
        __syncthreads();
        #pragma unroll
        for (int kk = 0; kk < BKF; ++kk) {
            float av[8], bv[8];
            *(float4*)&av[0] = *(const float4*)&As[kk][ty * 8];
            *(float4*)&av[4] = *(const float4*)&As[kk][ty * 8 + 4];
            *(float4*)&bv[0] = *(const float4*)&Bs[kk][tx * 8];
            *(float4*)&bv[4] = *(const float4*)&Bs[kk][tx * 8 + 4];
            #pragma unroll
            for (int i = 0; i < 8; ++i)
                #pragma unroll
                for (int j = 0; j < 8; ++j)
                    acc[i][j] = fmaf(av[i], bv[j], acc[i][j]);
        }
    }

    #pragma unroll
    for (int i = 0; i < 8; ++i) {
        float* crow = C + (size_t)(m0 + ty * 8 + i) * DIM + nb + tx * 8;
        *(float4*)crow       = make_float4(acc[i][0], acc[i][1], acc[i][2], acc[i][3]);
        *(float4*)(crow + 4) = make_float4(acc[i][4], acc[i][5], acc[i][6], acc[i][7]);
    }
}

// ---------------------------------------------------------------- epilogue (fallback path only)
__global__ __launch_bounds__(256) void ladder_epilogue(
    const float* __restrict__ X,
    const float* __restrict__ G,
    const float* __restrict__ Lw,
    const float* __restrict__ Vw,
    float* __restrict__ Out)
{
    const int r = blockIdx.x;
    const int tid = threadIdx.x;
    const int d0 = tid * 8;
    const float* xrow = X + (size_t)r * DIM;
    const float* grow = G + (size_t)r * DIM;

    const float4 xv0 = *(const float4*)(xrow + d0);
    const float4 xv1 = *(const float4*)(xrow + d0 + 4);
    const float4 gv0 = *(const float4*)(grow + d0);
    const float4 gv1 = *(const float4*)(grow + d0 + 4);

    float gated[8];
    {
        const float gx[8] = {gv0.x, gv0.y, gv0.z, gv0.w, gv1.x, gv1.y, gv1.z, gv1.w};
        const float xx[8] = {xv0.x, xv0.y, xv0.z, xv0.w, xv1.x, xv1.y, xv1.z, xv1.w};
        #pragma unroll
        for (int j = 0; j < 8; ++j) {
            const float s = 1.0f / (1.0f + __expf(-gx[j]));
            gated[j] = s * xx[j];
        }
    }

    float part[NLK];
    #pragma unroll
    for (int lk = 0; lk < NLK; ++lk) {
        const float* lrow = Lw + (size_t)lk * DIM + d0;
        const float4 w0 = *(const float4*)lrow;
        const float4 w1 = *(const float4*)(lrow + 4);
        part[lk] = gated[0] * w0.x + gated[1] * w0.y + gated[2] * w0.z + gated[3] * w0.w
                 + gated[4] * w1.x + gated[5] * w1.y + gated[6] * w1.z + gated[7] * w1.w;
    }

    #pragma unroll
    for (int off = 32; off > 0; off >>= 1) {
        #pragma unroll
        for (int lk = 0; lk < NLK; ++lk)
            part[lk] += __shfl_down(part[lk], off, 64);
    }

    __shared__ float red[4][NLK];
    __shared__ float zsh[NL];
    const int wave = tid >> 6;
    const int lane = tid & 63;
    if (lane == 0) {
        #pragma unroll
        for (int lk = 0; lk < NLK; ++lk) red[wave][lk] = part[lk];
    }
    __syncthreads();
    if (tid < NL) {
        float a[DEPTH + 1];
        #pragma unroll
        for (int k = 0; k < DEPTH + 1; ++k)
            a[k] = red[0][tid * 6 + k] + red[1][tid * 6 + k]
                 + red[2][tid * 6 + k] + red[3][tid * 6 + k];
        float f = 0.f;
        #pragma unroll
        for (int k = DEPTH - 1; k >= 0; --k) {
            float denom = 1.f + f;
            if (fabsf(denom) < CF_EPS) denom = (denom >= 0.f) ? CF_EPS : -CF_EPS;
            f = a[k + 1] / denom;
        }
        zsh[tid] = a[0] + f;
    }
    __syncthreads();
    const float z0 = zsh[0], z1 = zsh[1], z2 = zsh[2];

    float* orow = Out + (size_t)r * DIM + d0;
    const float4 o0 = *(const float4*)orow;
    const float4 o1 = *(const float4*)(orow + 4);
    float ov[8] = {o0.x, o0.y, o0.z, o0.w, o1.x, o1.y, o1.z, o1.w};
    #pragma unroll
    for (int j = 0; j < 8; ++j) {
        const float* vp = Vw + (size_t)(d0 + j) * NL;
        ov[j] += z0 * vp[0] + z1 * vp[1] + z2 * vp[2];
    }
    *(float4*)orow       = make_float4(ov[0], ov[1], ov[2], ov[3]);
    *(float4*)(orow + 4) = make_float4(ov[4], ov[5], ov[6], ov[7]);
}

// ---------------------------------------------------------------- launch
extern "C" void kernel_launch(void* const* d_in, const int* in_sizes, int n_in,
                              void* d_out, int out_size, void* d_ws, size_t ws_size,
                              hipStream_t stream) {
    const float* X  = (const float*)d_in[0];
    const float* Uw = (const float*)d_in[1];
    const float* Gw = (const float*)d_in[2];
    const float* Lw = (const float*)d_in[3];
    const float* Vw = (const float*)d_in[4];
    float* out = (float*)d_out;

    // ws layout (bytes):
    //   Xh  bf16    @ 0           33554432
    //   Xl  bf16    @ 33554432    33554432
    //   Gwh bf16    @ 67108864     8388608
    //   Gwl bf16    @ 75497472     8388608
    //   Uwh bf16    @ 83886080     8388608
    //   a_part f32  @ 92274688     9437184   (8192 x 16 x 18)
    //   z_buf f32   @ 101711872     131072   (8192 x 4)
    const size_t WS_NEED = 101842944ull;
    char* ws = (char*)d_ws;

    if (ws_size >= WS_NEED) {
        ushort* Xh     = (ushort*)(ws);
        ushort* Xl     = (ushort*)(ws + 33554432);
        ushort* Gwh    = (ushort*)(ws + 67108864);
        ushort* Gwl    = (ushort*)(ws + 75497472);
        ushort* Uwh    = (ushort*)(ws + 83886080);
        float*  a_part = (float*)(ws + 92274688);
        float*  z_buf  = (float*)(ws + 101711872);

        split2<<<dim3(8192), dim3(256), 0, stream>>>(X, Xh, Xl);       // 16.78M elems
        split2<<<dim3(2048), dim3(256), 0, stream>>>(Gw, Gwh, Gwl);    // 4.19M elems
        tobf16<<<dim3(2048), dim3(256), 0, stream>>>(Uw, Uwh);

        dim3 grid(DIM / 128, NROWS / 128);   // (16, 64)
        mfma_gemm_fused<<<grid, dim3(512), 0, stream>>>(Xh, Xl, Gwh, Gwl, Uwh,
                                                        X, Lw, out, a_part);
        cf_kernel<<<dim3(32), dim3(256), 0, stream>>>(a_part, z_buf);
        zv_add<<<dim3(NROWS), dim3(256), 0, stream>>>(out, z_buf, Vw);
    } else {
        // fallback: round-1 fp32 path (needs only 64 MB ws)
        float* gbuf = (float*)ws;
        dim3 grid(2 * DIM / BNF, NROWS / BMF);
        sgemm_dual<<<grid, dim3(256), 0, stream>>>(X, Uw, Gw, out, gbuf);
        ladder_epilogue<<<dim3(NROWS), dim3(256), 0, stream>>>(X, gbuf, Lw, Vw, out);
    }
}

// Round 11
// 478.723 us; speedup vs baseline: 1.2960x; 1.0417x over previous
//
#include <hip/hip_runtime.h>
#include <cstdint>
#include <cstddef>

#define DIM 2048
#define NROWS 8192
#define NL 3
#define DEPTH 5
#define NLK 18            // NL*(DEPTH+1)
#define NCB 16            // col-blocks (DIM/128) contributing partials per row
#define CF_EPS 0.01f

// ---------------------------------------------------------------- MFMA GEMM
typedef __attribute__((ext_vector_type(8))) __bf16 bfrag;   // 8 bf16 = 4 VGPRs
typedef __attribute__((ext_vector_type(4))) float f32x4;

typedef __attribute__((address_space(1))) void gvoid;
typedef __attribute__((address_space(3))) void lvoid;

__device__ __forceinline__ void gld_lds16(const void* g, void* l) {
    // async global->LDS, 16B per lane, dest = wave-uniform base + lane*16
    __builtin_amdgcn_global_load_lds((gvoid*)g, (lvoid*)l, 16, 0, 0);
}

// ================================================================
// U GEMM + fused z*V^T epilogue (round-5-proven, best config):
//   out[r,c] = sum_k Xh[r,k]*Uwh[c,k]  +  z[r,0..2] . Vp[c,0..2]
// 128x128 tile, 256 thr = 4 waves (2x2), wave = 64x64.
// K-step = 64: TWO BK=32 sub-tiles staged per barrier pair
// ([2][128][32] LDS layout, 32KB total), halving the per-step fixed
// cost (stage + vmcnt(0) drain + barrier) of this 16-MFMA/step kernel.
// ================================================================
__global__ __launch_bounds__(256) void mfma_gemm_u(
    const ushort* __restrict__ A, const ushort* __restrict__ B,
    const float* __restrict__ zb, const float* __restrict__ Vp,
    float* __restrict__ C)
{
    constexpr int BK = 32;                       // per sub-tile
    constexpr int SUB = 128 * BK;                // ushorts per sub-tile
    __shared__ __align__(16) ushort sA[2 * SUB];
    __shared__ __align__(16) ushort sB[2 * SUB];

    const int tid  = threadIdx.x;
    const int wave = tid >> 6;
    const int lane = tid & 63;
    const int wm   = wave & 1;
    const int wn   = wave >> 1;
    const int m0   = blockIdx.y * 128;
    const int n0   = blockIdx.x * 128;

    // staging: wave w covers rows [w*32, w*32+32) of each 128x32 sub-tile,
    // lane -> row=lane>>2, 16B chunk=lane&3  (proven round-2 pattern)
    const size_t soff = (size_t)(wave * 32 + (lane >> 2)) * DIM + (lane & 3) * 8;
    const ushort* gA = A + (size_t)m0 * DIM + soff;
    const ushort* gB = B + (size_t)n0 * DIM + soff;

    ushort* lA0 = &sA[(wave * 32) * BK];         // khalf0 dest
    ushort* lA1 = &sA[(wave * 32 + 16) * BK];
    ushort* lB0 = &sB[(wave * 32) * BK];
    ushort* lB1 = &sB[(wave * 32 + 16) * BK];

    const int fm = lane & 15;
    const int fq = lane >> 4;

    f32x4 acc[4][4];
    #pragma unroll
    for (int i = 0; i < 4; ++i)
        #pragma unroll
        for (int j = 0; j < 4; ++j)
            acc[i][j] = (f32x4){0.f, 0.f, 0.f, 0.f};

    for (int k0 = 0; k0 < DIM; k0 += 2 * BK) {
        __syncthreads();                          // previous step consumed
        // khalf0: global k in [k0, k0+32)
        gld_lds16(gA + k0, lA0);
        gld_lds16(gA + (size_t)16 * DIM + k0, lA1);
        gld_lds16(gB + k0, lB0);
        gld_lds16(gB + (size_t)16 * DIM + k0, lB1);
        // khalf1: global k in [k0+32, k0+64), dest second sub-tile
        gld_lds16(gA + k0 + BK, lA0 + SUB);
        gld_lds16(gA + (size_t)16 * DIM + k0 + BK, lA1 + SUB);
        gld_lds16(gB + k0 + BK, lB0 + SUB);
        gld_lds16(gB + (size_t)16 * DIM + k0 + BK, lB1 + SUB);
        __syncthreads();                          // vmcnt(0) drained by barrier

        #pragma unroll
        for (int ks = 0; ks < 2; ++ks) {
            const ushort* pA = &sA[ks * SUB];
            const ushort* pB = &sB[ks * SUB];
            bfrag ah[4], bh[4];
            #pragma unroll
            for (int i = 0; i < 4; ++i) {
                ah[i] = *(const bfrag*)&pA[(wm * 64 + i * 16 + fm) * BK + fq * 8];
                bh[i] = *(const bfrag*)&pB[(wn * 64 + i * 16 + fm) * BK + fq * 8];
            }
            #pragma unroll
            for (int i = 0; i < 4; ++i)
                #pragma unroll
                for (int j = 0; j < 4; ++j)
                    acc[i][j] = __builtin_amdgcn_mfma_f32_16x16x32_bf16(ah[i], bh[j], acc[i][j], 0, 0, 0);
        }
    }

    // C/D layout: col = lane&15, row = (lane>>4)*4 + reg.  Fused: + z[row].V[col]
    float4 vc[4];
    #pragma unroll
    for (int j = 0; j < 4; ++j)
        vc[j] = *(const float4*)&Vp[(size_t)(n0 + wn * 64 + j * 16 + fm) * 4];

    #pragma unroll
    for (int i = 0; i < 4; ++i) {
        const int rowb = m0 + wm * 64 + i * 16 + fq * 4;
        #pragma unroll
        for (int r = 0; r < 4; ++r) {
            const float4 zr = *(const float4*)&zb[(size_t)(rowb + r) * 4];
            #pragma unroll
            for (int j = 0; j < 4; ++j) {
                const int col = n0 + wn * 64 + j * 16 + fm;
                C[(size_t)(rowb + r) * DIM + col] =
                    acc[i][j][r] + zr.x * vc[j].x + zr.y * vc[j].y + zr.z * vc[j].z;
            }
        }
    }
}

// ================================================================
// Gate GEMM (split-bf16, 3 MFMA) + fused gated-ladder reduction.
//   a_part[(row*NCB + cb)*NLK + lk] = sum_{c in tile} sig(g[r,c])*x[r,c]*Lw[lk,c]
// NO atomics: per-block partial stores, reduced in cf_kernel.
// Epilogue quarter-loop is FULLY STATIC (rule #20).
// LDS epilogue aliases the (dead) staging buffers; total stays 32KB.
// (Proven at ~252us / MfmaUtil 36.5% — the m97-structure ceiling.)
// ================================================================
__global__ __launch_bounds__(256) void mfma_gemm_gate(
    const ushort* __restrict__ Ah, const ushort* __restrict__ Al,
    const ushort* __restrict__ Bh, const ushort* __restrict__ Bl,
    const float* __restrict__ X,  const float* __restrict__ Lw,
    float* __restrict__ a_part)
{
    constexpr int BK = 32;
    // [0,32768): staging 4 x 128x32 bf16 tiles (8KB each)
    // epilogue aliases: sG [0,16896) = 32x132 fp32 ; sLw [16896,28128) = 18x156 fp32
    __shared__ __align__(16) char smem[32768];
    ushort* sAh = (ushort*)(smem);
    ushort* sBh = (ushort*)(smem + 8192);
    ushort* sAl = (ushort*)(smem + 16384);
    ushort* sBl = (ushort*)(smem + 24576);
    float*  sG  = (float*)(smem);            // quarter-tile of gated values
    float*  sLw = (float*)(smem + 16896);    // ladder weights, strip-swizzled

    const int tid  = threadIdx.x;
    const int wave = tid >> 6;
    const int lane = tid & 63;
    const int wm   = wave & 1;
    const int wn   = wave >> 1;
    const int m0   = blockIdx.y * 128;
    const int n0   = blockIdx.x * 128;

    const size_t soff = (size_t)(wave * 32 + (lane >> 2)) * DIM + (lane & 3) * 8;
    const ushort* gA  = Ah + (size_t)m0 * DIM + soff;
    const ushort* gAl = Al + (size_t)m0 * DIM + soff;
    const ushort* gB  = Bh + (size_t)n0 * DIM + soff;
    const ushort* gBl = Bl + (size_t)n0 * DIM + soff;

    ushort* lA0  = &sAh[(wave * 32) * BK];
    ushort* lA1  = &sAh[(wave * 32 + 16) * BK];
    ushort* lB0  = &sBh[(wave * 32) * BK];
    ushort* lB1  = &sBh[(wave * 32 + 16) * BK];
    ushort* lAl0 = &sAl[(wave * 32) * BK];
    ushort* lAl1 = &sAl[(wave * 32 + 16) * BK];
    ushort* lBl0 = &sBl[(wave * 32) * BK];
    ushort* lBl1 = &sBl[(wave * 32 + 16) * BK];

    const int fm = lane & 15;
    const int fq = lane >> 4;

    f32x4 acc[4][4];
    #pragma unroll
    for (int i = 0; i < 4; ++i)
        #pragma unroll
        for (int j = 0; j < 4; ++j)
            acc[i][j] = (f32x4){0.f, 0.f, 0.f, 0.f};

    for (int k0 = 0; k0 < DIM; k0 += BK) {
        __syncthreads();
        gld_lds16(gA + k0, lA0);
        gld_lds16(gA + (size_t)16 * DIM + k0, lA1);
        gld_lds16(gB + k0, lB0);
        gld_lds16(gB + (size_t)16 * DIM + k0, lB1);
        gld_lds16(gAl + k0, lAl0);
        gld_lds16(gAl + (size_t)16 * DIM + k0, lAl1);
        gld_lds16(gBl + k0, lBl0);
        gld_lds16(gBl + (size_t)16 * DIM + k0, lBl1);
        __syncthreads();

        bfrag ah[4], bh[4], al[4], bl[4];
        #pragma unroll
        for (int i = 0; i < 4; ++i) {
            ah[i] = *(const bfrag*)&sAh[(wm * 64 + i * 16 + fm) * BK + fq * 8];
            bh[i] = *(const bfrag*)&sBh[(wn * 64 + i * 16 + fm) * BK + fq * 8];
            al[i] = *(const bfrag*)&sAl[(wm * 64 + i * 16 + fm) * BK + fq * 8];
            bl[i] = *(const bfrag*)&sBl[(wn * 64 + i * 16 + fm) * BK + fq * 8];
        }
        #pragma unroll
        for (int i = 0; i < 4; ++i)
            #pragma unroll
            for (int j = 0; j < 4; ++j) {
                acc[i][j] = __builtin_amdgcn_mfma_f32_16x16x32_bf16(ah[i], bh[j], acc[i][j], 0, 0, 0);
                acc[i][j] = __builtin_amdgcn_mfma_f32_16x16x32_bf16(ah[i], bl[j], acc[i][j], 0, 0, 0);
                acc[i][j] = __builtin_amdgcn_mfma_f32_16x16x32_bf16(al[i], bh[j], acc[i][j], 0, 0, 0);
            }
    }

    // ---- fused gated-ladder reduction, four 32-row quarters (STATIC) ----
    const float* xblk = X + (size_t)m0 * DIM + n0;
    const int rred  = ((tid >> 6) << 3) | (tid & 7);   // reduce row 0..31
    const int strip = (lane >> 3) & 7;                 // 8 strips x 16 cols
    const int qc    = strip * 16;

#define DO_QUARTER(Q)                                                          \
    {                                                                          \
        __syncthreads();  /* staging (Q==0) / previous-quarter reads done */   \
        if (Q == 0) {                                                          \
            /* ladder weights, strip-swizzled (+4 dwords per 16-col strip) */  \
            for (int idx = tid; idx < NLK * 128; idx += 256) {                 \
                const int lk = idx >> 7, c = idx & 127;                        \
                sLw[lk * 156 + c + ((c >> 4) << 2)] = Lw[(size_t)lk * DIM + n0 + c]; \
            }                                                                  \
        }                                                                      \
        if (wm == (Q >> 1)) {                                                  \
            constexpr int ib = (Q & 1) * 2;  /* compile-time: keeps acc in VGPRs */ \
            _Pragma("unroll")                                                  \
            for (int ii = 0; ii < 2; ++ii) {                                   \
                _Pragma("unroll")                                              \
                for (int r = 0; r < 4; ++r) {                                  \
                    const int rloc = ii * 16 + fq * 4 + r;      /* 0..31 */    \
                    const float* xr = xblk + (size_t)(Q * 32 + rloc) * DIM;    \
                    _Pragma("unroll")                                          \
                    for (int j = 0; j < 4; ++j) {                              \
                        const int cc = wn * 64 + j * 16 + fm;                  \
                        const float g = acc[ib + ii][j][r];                    \
                        const float s = 1.0f / (1.0f + __expf(-g));            \
                        sG[rloc * 132 + cc] = s * xr[cc];                      \
                    }                                                          \
                }                                                              \
            }                                                                  \
        }                                                                      \
        __syncthreads();   /* sG (+ sLw at Q==0) ready */                      \
        float p[NLK];                                                          \
        _Pragma("unroll")                                                      \
        for (int lk = 0; lk < NLK; ++lk) p[lk] = 0.f;                          \
        _Pragma("unroll")                                                      \
        for (int c4 = 0; c4 < 16; c4 += 4) {                                   \
            const float4 g4 = *(const float4*)&sG[rred * 132 + qc + c4];       \
            _Pragma("unroll")                                                  \
            for (int lk = 0; lk < NLK; ++lk) {                                 \
                const float4 w4 = *(const float4*)&sLw[lk * 156 + qc + c4 + (strip << 2)]; \
                p[lk] = fmaf(g4.x, w4.x, fmaf(g4.y, w4.y,                      \
                        fmaf(g4.z, w4.z, fmaf(g4.w, w4.w, p[lk]))));           \
            }                                                                  \
        }                                                                      \
        _Pragma("unroll")                                                      \
        for (int lk = 0; lk < NLK; ++lk) {                                     \
            p[lk] += __shfl_xor(p[lk], 8, 64);                                 \
            p[lk] += __shfl_xor(p[lk], 16, 64);                                \
            p[lk] += __shfl_xor(p[lk], 32, 64);                                \
        }                                                                      \
        if ((lane >> 3) == 0) {                                                \
            float* dst = a_part +                                              \
                ((size_t)(m0 + Q * 32 + rred) * NCB + blockIdx.x) * NLK;       \
            _Pragma("unroll")                                                  \
            for (int lk = 0; lk < NLK; ++lk) dst[lk] = p[lk];                  \
        }                                                                      \
    }

    DO_QUARTER(0)
    DO_QUARTER(1)
    DO_QUARTER(2)
    DO_QUARTER(3)
#undef DO_QUARTER
}

// ================================================================
// reduce partials + continued fraction:
//   a_part[8192][NCB][18] -> z_buf[8192][4]
// The 288 floats per row are CONTIGUOUS: load as 72 fully-unrolled
// float4 (bin index (q*4+c)%18 is compile-time -> a[] stays in VGPRs,
// rule #20), vs the previous 288 scalar loads. 128 blocks x 64 thr
// spreads the 8192 rows across 128 CUs (was 32).
// ================================================================
__global__ __launch_bounds__(64) void cf_kernel(const float* __restrict__ a_part,
                                                float* __restrict__ zb)
{
    const int r = blockIdx.x * 64 + threadIdx.x;
    const float* ap = a_part + (size_t)r * NCB * NLK;   // 288 contiguous floats
    float a[NLK];
    #pragma unroll
    for (int lk = 0; lk < NLK; ++lk) a[lk] = 0.f;
    #pragma unroll
    for (int q = 0; q < 72; ++q) {
        const float4 v = *(const float4*)(ap + q * 4);
        a[(q * 4 + 0) % NLK] += v.x;
        a[(q * 4 + 1) % NLK] += v.y;
        a[(q * 4 + 2) % NLK] += v.z;
        a[(q * 4 + 3) % NLK] += v.w;
    }
    float z[NL];
    #pragma unroll
    for (int l = 0; l < NL; ++l) {
        float f = 0.f;
        #pragma unroll
        for (int k = DEPTH - 1; k >= 0; --k) {
            float denom = 1.f + f;
            if (fabsf(denom) < CF_EPS) denom = (denom >= 0.f) ? CF_EPS : -CF_EPS;
            f = a[l * (DEPTH + 1) + k + 1] / denom;
        }
        z[l] = a[l * (DEPTH + 1)] + f;
    }
    *(float4*)&zb[(size_t)r * 4] = make_float4(z[0], z[1], z[2], 0.f);
}

// V_w [2048][3] -> padded [2048][4] for aligned float4 loads
__global__ __launch_bounds__(256) void padV(const float* __restrict__ Vw,
                                            float* __restrict__ Vp)
{
    const int d = blockIdx.x * 256 + threadIdx.x;
    *(float4*)&Vp[(size_t)d * 4] =
        make_float4(Vw[(size_t)d * 3], Vw[(size_t)d * 3 + 1], Vw[(size_t)d * 3 + 2], 0.f);
}

// ---------------------------------------------------------------- prep
__device__ __forceinline__ ushort f2bf_bits(float f) {
    __bf16 h = (__bf16)f;                        // RNE
    return __builtin_bit_cast(unsigned short, h);
}
__device__ __forceinline__ float bfbits2f(ushort u) {
    __bf16 h = __builtin_bit_cast(__bf16, u);
    return (float)h;
}

union U16x8 { ushort u[8]; uint4 v; };

__global__ __launch_bounds__(256) void split2(const float* __restrict__ src,
                                              ushort* __restrict__ hi,
                                              ushort* __restrict__ lo)
{
    const size_t i0 = ((size_t)blockIdx.x * 256 + threadIdx.x) * 8;
    const float4 v0 = *(const float4*)(src + i0);
    const float4 v1 = *(const float4*)(src + i0 + 4);
    const float f[8] = {v0.x, v0.y, v0.z, v0.w, v1.x, v1.y, v1.z, v1.w};
    U16x8 h, l;
    #pragma unroll
    for (int j = 0; j < 8; ++j) {
        const ushort hb = f2bf_bits(f[j]);
        h.u[j] = hb;
        l.u[j] = f2bf_bits(f[j] - bfbits2f(hb));
    }
    *(uint4*)(hi + i0) = h.v;
    *(uint4*)(lo + i0) = l.v;
}

__global__ __launch_bounds__(256) void tobf16(const float* __restrict__ src,
                                              ushort* __restrict__ dst)
{
    const size_t i0 = ((size_t)blockIdx.x * 256 + threadIdx.x) * 8;
    const float4 v0 = *(const float4*)(src + i0);
    const float4 v1 = *(const float4*)(src + i0 + 4);
    const float f[8] = {v0.x, v0.y, v0.z, v0.w, v1.x, v1.y, v1.z, v1.w};
    U16x8 h;
    #pragma unroll
    for (int j = 0; j < 8; ++j) h.u[j] = f2bf_bits(f[j]);
    *(uint4*)(dst + i0) = h.v;
}

// ---------------------------------------------------------------- fp32 fallback GEMM (round-1, proven)
#define BMF 128
#define BNF 128
#define BKF 16
#define LDAF 132

__global__ __launch_bounds__(256) void sgemm_dual(
    const float* __restrict__ X,
    const float* __restrict__ Uw,
    const float* __restrict__ Gw,
    float* __restrict__ outLin,
    float* __restrict__ outGate)
{
    __shared__ float As[BKF][LDAF];
    __shared__ float Bs[BKF][LDAF];

    const int tid = threadIdx.x;
    const int n0 = blockIdx.x * BNF;
    const int m0 = blockIdx.y * BMF;
    const bool isGate = (n0 >= DIM);
    const float* W = isGate ? Gw : Uw;
    float* C = isGate ? outGate : outLin;
    const int nb = isGate ? (n0 - DIM) : n0;

    const int lr = tid >> 2;
    const int lc = (tid & 3) << 2;

    const float* pa0 = X + (size_t)(m0 + lr) * DIM + lc;
    const float* pa1 = X + (size_t)(m0 + lr + 64) * DIM + lc;
    const float* pb0 = W + (size_t)(nb + lr) * DIM + lc;
    const float* pb1 = W + (size_t)(nb + lr + 64) * DIM + lc;

    const int tx = tid & 15;
    const int ty = tid >> 4;

    float acc[8][8];
    #pragma unroll
    for (int i = 0; i < 8; ++i)
        #pragma unroll
        for (int j = 0; j < 8; ++j) acc[i][j] = 0.f;

    for (int k0 = 0; k0 < DIM; k0 += BKF) {
        const float4 a0 = *(const float4*)(pa0 + k0);
        const float4 a1 = *(const float4*)(pa1 + k0);
        const float4 b0 = *(const float4*)(pb0 + k0);
        const float4 b1 = *(const float4*)(pb1 + k0);
        __syncthreads();
        As[lc + 0][lr] = a0.x; As[lc + 1][lr] = a0.y; As[lc + 2][lr] = a0.z; As[lc + 3][lr] = a0.w;
        As[lc + 0][lr + 64] = a1.x; As[lc + 1][lr + 64] = a1.y; As[lc + 2][lr + 64] = a1.z; As[lc + 3][lr + 64] = a1.w;
        Bs[lc + 0][lr] = b0.x; Bs[lc + 1][lr] = b0.y; Bs[lc + 2][lr] = b0.z; Bs[lc + 3][lr] = b0.w;
        Bs[lc + 0][lr + 64] = b1.x; Bs[lc + 1][lr + 64] = b1.y; Bs[lc + 2][lr + 64] = b1.z; Bs[lc + 3][lr + 64] = b1.w;
        __syncthreads();
        #pragma unroll
        for (int kk = 0; kk < BKF; ++kk) {
            float av[8], bv[8];
            *(float4*)&av[0] = *(const float4*)&As[kk][ty * 8];
            *(float4*)&av[4] = *(const float4*)&As[kk][ty * 8 + 4];
            *(float4*)&bv[0] = *(const float4*)&Bs[kk][tx * 8];
            *(float4*)&bv[4] = *(const float4*)&Bs[kk][tx * 8 + 4];
            #pragma unroll
            for (int i = 0; i < 8; ++i)
                #pragma unroll
                for (int j = 0; j < 8; ++j)
                    acc[i][j] = fmaf(av[i], bv[j], acc[i][j]);
        }
    }

    #pragma unroll
    for (int i = 0; i < 8; ++i) {
        float* crow = C + (size_t)(m0 + ty * 8 + i) * DIM + nb + tx * 8;
        *(float4*)crow       = make_float4(acc[i][0], acc[i][1], acc[i][2], acc[i][3]);
        *(float4*)(crow + 4) = make_float4(acc[i][4], acc[i][5], acc[i][6], acc[i][7]);
    }
}

// ---------------------------------------------------------------- epilogue (fallback path only)
__global__ __launch_bounds__(256) void ladder_epilogue(
    const float* __restrict__ X,
    const float* __restrict__ G,
    const float* __restrict__ Lw,
    const float* __restrict__ Vw,
    float* __restrict__ Out)
{
    const int r = blockIdx.x;
    const int tid = threadIdx.x;
    const int d0 = tid * 8;
    const float* xrow = X + (size_t)r * DIM;
    const float* grow = G + (size_t)r * DIM;

    const float4 xv0 = *(const float4*)(xrow + d0);
    const float4 xv1 = *(const float4*)(xrow + d0 + 4);
    const float4 gv0 = *(const float4*)(grow + d0);
    const float4 gv1 = *(const float4*)(grow + d0 + 4);

    float gated[8];
    {
        const float gx[8] = {gv0.x, gv0.y, gv0.z, gv0.w, gv1.x, gv1.y, gv1.z, gv1.w};
        const float xx[8] = {xv0.x, xv0.y, xv0.z, xv0.w, xv1.x, xv1.y, xv1.z, xv1.w};
        #pragma unroll
        for (int j = 0; j < 8; ++j) {
            const float s = 1.0f / (1.0f + __expf(-gx[j]));
            gated[j] = s * xx[j];
        }
    }

    float part[NLK];
    #pragma unroll
    for (int lk = 0; lk < NLK; ++lk) {
        const float* lrow = Lw + (size_t)lk * DIM + d0;
        const float4 w0 = *(const float4*)lrow;
        const float4 w1 = *(const float4*)(lrow + 4);
        part[lk] = gated[0] * w0.x + gated[1] * w0.y + gated[2] * w0.z + gated[3] * w0.w
                 + gated[4] * w1.x + gated[5] * w1.y + gated[6] * w1.z + gated[7] * w1.w;
    }

    #pragma unroll
    for (int off = 32; off > 0; off >>= 1) {
        #pragma unroll
        for (int lk = 0; lk < NLK; ++lk)
            part[lk] += __shfl_down(part[lk], off, 64);
    }

    __shared__ float red[4][NLK];
    __shared__ float zsh[NL];
    const int wave = tid >> 6;
    const int lane = tid & 63;
    if (lane == 0) {
        #pragma unroll
        for (int lk = 0; lk < NLK; ++lk) red[wave][lk] = part[lk];
    }
    __syncthreads();
    if (tid < NL) {
        float a[DEPTH + 1];
        #pragma unroll
        for (int k = 0; k < DEPTH + 1; ++k)
            a[k] = red[0][tid * 6 + k] + red[1][tid * 6 + k]
                 + red[2][tid * 6 + k] + red[3][tid * 6 + k];
        float f = 0.f;
        #pragma unroll
        for (int k = DEPTH - 1; k >= 0; --k) {
            float denom = 1.f + f;
            if (fabsf(denom) < CF_EPS) denom = (denom >= 0.f) ? CF_EPS : -CF_EPS;
            f = a[k + 1] / denom;
        }
        zsh[tid] = a[0] + f;
    }
    __syncthreads();
    const float z0 = zsh[0], z1 = zsh[1], z2 = zsh[2];

    float* orow = Out + (size_t)r * DIM + d0;
    const float4 o0 = *(const float4*)orow;
    const float4 o1 = *(const float4*)(orow + 4);
    float ov[8] = {o0.x, o0.y, o0.z, o0.w, o1.x, o1.y, o1.z, o1.w};
    #pragma unroll
    for (int j = 0; j < 8; ++j) {
        const float* vp = Vw + (size_t)(d0 + j) * NL;
        ov[j] += z0 * vp[0] + z1 * vp[1] + z2 * vp[2];
    }
    *(float4*)orow       = make_float4(ov[0], ov[1], ov[2], ov[3]);
    *(float4*)(orow + 4) = make_float4(ov[4], ov[5], ov[6], ov[7]);
}

// ---------------------------------------------------------------- launch
extern "C" void kernel_launch(void* const* d_in, const int* in_sizes, int n_in,
                              void* d_out, int out_size, void* d_ws, size_t ws_size,
                              hipStream_t stream) {
    const float* X  = (const float*)d_in[0];
    const float* Uw = (const float*)d_in[1];
    const float* Gw = (const float*)d_in[2];
    const float* Lw = (const float*)d_in[3];
    const float* Vw = (const float*)d_in[4];
    float* out = (float*)d_out;

    // ws layout (bytes):
    //   Xh  bf16    @ 0           33554432
    //   Xl  bf16    @ 33554432    33554432
    //   Gwh bf16    @ 67108864     8388608
    //   Gwl bf16    @ 75497472     8388608
    //   Uwh bf16    @ 83886080     8388608
    //   a_part f32  @ 92274688     9437184   (8192 x 16 x 18)
    //   z_buf f32   @ 101711872     131072   (8192 x 4)
    //   Vp  f32     @ 101842944      32768   (2048 x 4)
    const size_t WS_NEED = 101875712ull;
    char* ws = (char*)d_ws;

    if (ws_size >= WS_NEED) {
        ushort* Xh     = (ushort*)(ws);
        ushort* Xl     = (ushort*)(ws + 33554432);
        ushort* Gwh    = (ushort*)(ws + 67108864);
        ushort* Gwl    = (ushort*)(ws + 75497472);
        ushort* Uwh    = (ushort*)(ws + 83886080);
        float*  a_part = (float*)(ws + 92274688);
        float*  z_buf  = (float*)(ws + 101711872);
        float*  Vp     = (float*)(ws + 101842944);

        split2<<<dim3(8192), dim3(256), 0, stream>>>(X, Xh, Xl);       // 16.78M elems
        split2<<<dim3(2048), dim3(256), 0, stream>>>(Gw, Gwh, Gwl);    // 4.19M elems
        tobf16<<<dim3(2048), dim3(256), 0, stream>>>(Uw, Uwh);
        padV  <<<dim3(8),    dim3(256), 0, stream>>>(Vw, Vp);

        dim3 grid(DIM / 128, NROWS / 128);   // (16, 64)
        mfma_gemm_gate<<<grid, dim3(256), 0, stream>>>(Xh, Xl, Gwh, Gwl, X, Lw, a_part);
        cf_kernel<<<dim3(128), dim3(64), 0, stream>>>(a_part, z_buf);
        mfma_gemm_u<<<grid, dim3(256), 0, stream>>>(Xh, Uwh, z_buf, Vp, out);
    } else {
        // fallback: round-1 fp32 path (needs only 64 MB ws)
        float* gbuf = (float*)ws;
        dim3 grid(2 * DIM / BNF, NROWS / BMF);
        sgemm_dual<<<grid, dim3(256), 0, stream>>>(X, Uw, Gw, out, gbuf);
        ladder_epilogue<<<dim3(NROWS), dim3(256), 0, stream>>>(X, gbuf, Lw, Vw, out);
    }
}